// Round 2
// baseline (883.412 us; speedup 1.0000x reference)
//
#include <hip/hip_runtime.h>
#include <stdint.h>

// Problem constants (B=4, Q=4096, V=4096, H=128, fp32 in/out)
#define NB 4
#define NQ 4096
#define NV 4096
#define HD 128
#define SCALE_F 11.31370849898476f      // sqrt(128), fp32

#define ROWS_PER_BLOCK 16               // 4 waves x 4 rows
#define ROWS_PER_WAVE 4
#define VT 64                           // v-tile size
#define LSTR 132                        // padded LDS row stride (floats), 16B-aligned

// keep  <=>  uniform(bits) < 0.9f  <=>  (bits>>9) < 7549747  <=>  bits < 7549747*512
#define KEEP_THRESH 3865470464u

__device__ __forceinline__ uint32_t rotl(uint32_t x, int r) {
    return (x << r) | (x >> (32 - r));
}

// JAX threefry2x32, PARTITIONABLE path (default since JAX 0.4.36):
//   counts = iota(uint64, size); x_hi = counts>>32 (==0 here), x_lo = j
//   (y0,y1) = threefry2x32(key=(0,42), (x_hi, x_lo));  bits32 = y0 ^ y1
__device__ __forceinline__ uint32_t threefry_bits(uint32_t j) {
    uint32_t x0 = 0u;       // hi word of 64-bit counter (all counters < 2^32)
    uint32_t x1 = j;        // lo word
    const uint32_t k0 = 0u;
    const uint32_t k1 = 42u;
    const uint32_t k2 = 0u ^ 42u ^ 0x1BD11BDAu;
    x0 += k0; x1 += k1;
#define TFR4(a,b,c,d) \
    x0 += x1; x1 = rotl(x1, a); x1 ^= x0; \
    x0 += x1; x1 = rotl(x1, b); x1 ^= x0; \
    x0 += x1; x1 = rotl(x1, c); x1 ^= x0; \
    x0 += x1; x1 = rotl(x1, d); x1 ^= x0;
    TFR4(13, 15, 26, 6)
    x0 += k1; x1 += k2 + 1u;
    TFR4(17, 29, 16, 24)
    x0 += k2; x1 += k0 + 2u;
    TFR4(13, 15, 26, 6)
    x0 += k0; x1 += k1 + 3u;
    TFR4(17, 29, 16, 24)
    x0 += k1; x1 += k2 + 4u;
    TFR4(13, 15, 26, 6)
    x0 += k2; x1 += k0 + 5u;
#undef TFR4
    return x0 ^ x1;
}

__global__ __launch_bounds__(256)
void fused_attn_dropout(const float* __restrict__ Qg, const float* __restrict__ Kg,
                        const float* __restrict__ Vg, float* __restrict__ Og) {
    // Single K/V staging buffer (34 KB) + q rows (8 KB) + p broadcast (4 KB)
    __shared__ __align__(16) float kvls[VT * LSTR];
    __shared__ __align__(16) float qls[ROWS_PER_BLOCK][HD];
    __shared__ float pls[4][ROWS_PER_WAVE][VT];
    __shared__ int waveNeed[4];

    const int tid  = threadIdx.x;
    const int wave = tid >> 6;
    const int lane = tid & 63;
    const int blockRow0 = blockIdx.x * ROWS_PER_BLOCK;   // global row = b*NQ + q
    const int b = blockRow0 / NQ;                        // all 16 rows share b
    const int waveRow0 = blockRow0 + wave * ROWS_PER_WAVE;
    const size_t kvbase = (size_t)b * NV * HD;

    // stage all 16 q rows (coalesced float4)
    for (int idx = tid; idx < ROWS_PER_BLOCK * (HD / 4); idx += 256) {
        int r = idx >> 5;            // HD/4 = 32 float4 per row
        int c = idx & 31;
        float4 qv = *(const float4*)(Qg + (size_t)(blockRow0 + r) * HD + (size_t)c * 4);
        *(float4*)(&qls[r][c * 4]) = qv;
    }

    float  m_run[ROWS_PER_WAVE];
    float  l_run[ROWS_PER_WAVE];
    float2 acc[ROWS_PER_WAVE];
#pragma unroll
    for (int r = 0; r < ROWS_PER_WAVE; ++r) {
        m_run[r] = -INFINITY;
        l_run[r] = 0.f;
        acc[r] = make_float2(0.f, 0.f);
    }

    for (int v0 = 0; v0 < NV; v0 += VT) {
        __syncthreads();   // previous iteration's V reads complete before restage
        // stage K tile (64 x 128, coalesced float4)
        for (int idx = tid; idx < VT * (HD / 4); idx += 256) {
            int r = idx >> 5;
            int c = idx & 31;
            float4 kv = *(const float4*)(Kg + kvbase + (size_t)(v0 + r) * HD + (size_t)c * 4);
            *(float4*)(&kvls[r * LSTR + c * 4]) = kv;
        }
        __syncthreads();

        // scores: lane handles v = v0 + lane, for 4 rows
        float s[ROWS_PER_WAVE] = {0.f, 0.f, 0.f, 0.f};
        const float* krow = &kvls[lane * LSTR];
#pragma unroll
        for (int c = 0; c < HD / 4; ++c) {
            float4 kk = *(const float4*)(krow + c * 4);
#pragma unroll
            for (int r = 0; r < ROWS_PER_WAVE; ++r) {
                float4 qq = *(const float4*)(&qls[wave * ROWS_PER_WAVE + r][c * 4]);
                s[r] += qq.x * kk.x + qq.y * kk.y + qq.z * kk.z + qq.w * kk.w;
            }
        }

        bool  need[ROWS_PER_WAVE];
        float pv[ROWS_PER_WAVE];
#pragma unroll
        for (int r = 0; r < ROWS_PER_WAVE; ++r) {
            float sc = s[r] * SCALE_F;
            float tmax = sc;
#pragma unroll
            for (int off = 32; off > 0; off >>= 1)
                tmax = fmaxf(tmax, __shfl_xor(tmax, off));
            float m_new = fmaxf(m_run[r], tmax);
            float p = __expf(sc - m_new);
            float tsum = p;
#pragma unroll
            for (int off = 32; off > 0; off >>= 1)
                tsum += __shfl_xor(tsum, off);
            float alpha = __expf(m_run[r] - m_new);
            l_run[r] = l_run[r] * alpha + tsum;
            m_run[r] = m_new;
            acc[r].x *= alpha;
            acc[r].y *= alpha;
            // skipped tiles contribute < 1e-9 relative mass each -> |dOut| < ~1e-6 total
            need[r] = (tsum > 1e-9f * l_run[r]);
            pv[r] = p;
        }

        bool anyNeed = need[0] | need[1] | need[2] | need[3];
        if (lane == 0) waveNeed[wave] = anyNeed ? 1 : 0;
        __syncthreads();   // also guarantees all K reads are done
        int blockNeed = waveNeed[0] | waveNeed[1] | waveNeed[2] | waveNeed[3];

        if (blockNeed) {
            // stage V tile into the same buffer
            for (int idx = tid; idx < VT * (HD / 4); idx += 256) {
                int r = idx >> 5;
                int c = idx & 31;
                float4 vv = *(const float4*)(Vg + kvbase + (size_t)(v0 + r) * HD + (size_t)c * 4);
                *(float4*)(&kvls[r * LSTR + c * 4]) = vv;
            }
            __syncthreads();

            if (anyNeed) {
#pragma unroll
                for (int r = 0; r < ROWS_PER_WAVE; ++r) {
                    float peff = 0.f;
                    if (need[r]) {
                        uint32_t j = (uint32_t)(waveRow0 + r) * (uint32_t)NV
                                   + (uint32_t)(v0 + lane);
                        uint32_t bits = threefry_bits(j);
                        peff = (bits < KEEP_THRESH) ? pv[r] : 0.f;
                    }
                    pls[wave][r][lane] = peff;
                }
                // accumulate: lane owns h = 2*lane, 2*lane+1
                for (int v = 0; v < VT; ++v) {
                    float2 vv = *(const float2*)(&kvls[v * LSTR + 2 * lane]);
#pragma unroll
                    for (int r = 0; r < ROWS_PER_WAVE; ++r) {
                        float p = pls[wave][r][v];
                        acc[r].x += p * vv.x;
                        acc[r].y += p * vv.y;
                    }
                }
            }
        }
    }

    // epilogue: out = acc / (0.9 * l)
#pragma unroll
    for (int r = 0; r < ROWS_PER_WAVE; ++r) {
        float inv = 1.0f / (0.9f * l_run[r]);
        float2 o = make_float2(acc[r].x * inv, acc[r].y * inv);
        *(float2*)(Og + (size_t)(waveRow0 + r) * HD + 2 * lane) = o;
    }
}

extern "C" void kernel_launch(void* const* d_in, const int* in_sizes, int n_in,
                              void* d_out, int out_size, void* d_ws, size_t ws_size,
                              hipStream_t stream) {
    (void)in_sizes; (void)n_in; (void)out_size; (void)d_ws; (void)ws_size;
    const float* Qg = (const float*)d_in[0];
    const float* Kg = (const float*)d_in[1];
    const float* Vg = (const float*)d_in[2];
    float* Og = (float*)d_out;
    dim3 grid(NB * NQ / ROWS_PER_BLOCK);   // 1024 blocks
    fused_attn_dropout<<<grid, 256, 0, stream>>>(Qg, Kg, Vg, Og);
}

// Round 3
// 353.198 us; speedup vs baseline: 2.5012x; 2.5012x over previous
//
#include <hip/hip_runtime.h>
#include <stdint.h>

// B=4, Q=4096, V=4096, H=128, fp32 in/out
#define NBATCH 4
#define NQ 4096
#define NV 4096
#define HD 128

// SCALE * log2(e): scores scaled into exp2 domain
#define SCL2E ((float)(11.31370849898476 * 1.4426950408889634))

// keep  <=>  bits < 0.9f in fixed point (0.9f = 7549747 * 2^-23)
#define KEEP_THRESH 3865470464u
#define EPS_SKIP 1e-8f

#define KSTR 144   // khi/klo row stride (ushorts): 64 rows x 288 B (16B-aligned, ~2-way banks)
#define VSTR 76    // vt (V^T) row stride (ushorts): 128 rows x 152 B (8B-aligned, b64 reads)
#define PSTR 72    // pls row stride (ushorts): 16 rows x 144 B (16B-aligned b128 reads)

typedef __attribute__((ext_vector_type(8))) short short8;   // 8 bf16 = 4 VGPRs (MFMA A/B frag)
typedef __attribute__((ext_vector_type(4))) float floatx4;  // MFMA C/D frag
typedef unsigned int uint;
typedef unsigned short ushort;

__device__ __forceinline__ ushort bf16rne(float f) {
    uint u = __float_as_uint(f);
    u = (u + 0x7fffu + ((u >> 16) & 1u)) >> 16;
    return (ushort)u;
}
__device__ __forceinline__ float bf2f(ushort h) {
    return __uint_as_float(((uint)h) << 16);
}

__device__ __forceinline__ uint rotl(uint x, int r) { return (x << r) | (x >> (32 - r)); }

// JAX threefry2x32 partitionable path, key=(0,42): bits = y0 ^ y1 of hash of 64-bit counter j
__device__ __forceinline__ uint threefry_bits(uint j) {
    uint x0 = 0u;   // counter hi word (all j < 2^32)
    uint x1 = j;
    const uint k0 = 0u, k1 = 42u, k2 = 0u ^ 42u ^ 0x1BD11BDAu;
    x0 += k0; x1 += k1;
#define TFR4(a,b,c,d) \
    x0 += x1; x1 = rotl(x1, a); x1 ^= x0; \
    x0 += x1; x1 = rotl(x1, b); x1 ^= x0; \
    x0 += x1; x1 = rotl(x1, c); x1 ^= x0; \
    x0 += x1; x1 = rotl(x1, d); x1 ^= x0;
    TFR4(13, 15, 26, 6)
    x0 += k1; x1 += k2 + 1u;
    TFR4(17, 29, 16, 24)
    x0 += k2; x1 += k0 + 2u;
    TFR4(13, 15, 26, 6)
    x0 += k0; x1 += k1 + 3u;
    TFR4(17, 29, 16, 24)
    x0 += k1; x1 += k2 + 4u;
    TFR4(13, 15, 26, 6)
    x0 += k2; x1 += k0 + 5u;
#undef TFR4
    return x0 ^ x1;
}

// Fragment layouts (gfx950 mfma_f32_16x16x32_bf16, m89/m120-verified):
//   A: lane holds A[m = lane&15][k = (lane>>4)*8 + j], j=0..7
//   B: lane holds B[k = (lane>>4)*8 + j][n = lane&15]
//   C/D: lane holds D[row = (lane>>4)*4 + reg][col = lane&15]
__global__ __launch_bounds__(256)
void fa_mfma(const float* __restrict__ Qg, const float* __restrict__ Kg,
             const float* __restrict__ Vg, float* __restrict__ Og) {
    __shared__ ushort khi[64 * KSTR];        // K tile, bf16 hi   (18.4 KB)
    __shared__ ushort klo[64 * KSTR];        // K tile, bf16 lo   (18.4 KB)
    __shared__ ushort vt[128 * VSTR];        // V tile TRANSPOSED [h][v] (19.4 KB)
    __shared__ ushort pls[4][16 * PSTR];     // per-wave P round-trip     (9.2 KB)

    const int tid  = threadIdx.x;
    const int wave = tid >> 6;
    const int lane = tid & 63;
    const int r    = lane & 15;   // n / col index
    const int qd   = lane >> 4;   // quad
    const int blockRow0 = blockIdx.x * 64;
    const int b = blockRow0 >> 12;
    const int waveRow0 = blockRow0 + wave * 16;
    const size_t kvbase = (size_t)b * NV * HD;

    // ---- Q -> A-fragments (hi/lo bf16 split), held in registers ----
    short8 qfh[4], qfl[4];
    {
        const float* qp = Qg + (size_t)(waveRow0 + r) * HD + qd * 8;
#pragma unroll
        for (int kc = 0; kc < 4; ++kc) {
            float x[8];
            *(float4*)&x[0] = *(const float4*)(qp + kc * 32);
            *(float4*)&x[4] = *(const float4*)(qp + kc * 32 + 4);
#pragma unroll
            for (int j = 0; j < 8; ++j) {
                ushort h = bf16rne(x[j]);
                ushort l = bf16rne(x[j] - bf2f(h));
                qfh[kc][j] = (short)h;
                qfl[kc][j] = (short)l;
            }
        }
    }

    floatx4 oacc[8];
#pragma unroll
    for (int n = 0; n < 8; ++n) oacc[n] = (floatx4){0.f, 0.f, 0.f, 0.f};
    float m2[4] = {-INFINITY, -INFINITY, -INFINITY, -INFINITY};
    float lr[4] = {0.f, 0.f, 0.f, 0.f};

    for (int v0 = 0; v0 < NV; v0 += 64) {
        __syncthreads();   // everyone done reading previous tile's LDS

        // ---- stage K tile: fp32 -> bf16 hi/lo, row-major [v][h] ----
#pragma unroll
        for (int i = 0; i < 8; ++i) {
            int f = i * 256 + tid;
            int v = f >> 5;
            int h = (f & 31) * 4;
            float4 kv = *(const float4*)(Kg + kvbase + (size_t)(v0 + v) * HD + h);
            ushort4 hh, ll;
            hh.x = bf16rne(kv.x); ll.x = bf16rne(kv.x - bf2f(hh.x));
            hh.y = bf16rne(kv.y); ll.y = bf16rne(kv.y - bf2f(hh.y));
            hh.z = bf16rne(kv.z); ll.z = bf16rne(kv.z - bf2f(hh.z));
            hh.w = bf16rne(kv.w); ll.w = bf16rne(kv.w - bf2f(hh.w));
            *(ushort4*)&khi[v * KSTR + h] = hh;
            *(ushort4*)&klo[v * KSTR + h] = ll;
        }
        // ---- stage V tile transposed: vt[h][v] = bf16(V[v][h]) ----
        {
            int hp = tid & 63, rp = tid >> 6;
            int h = hp * 2;
            const float* vpb = Vg + kvbase + (size_t)v0 * HD + h;
#pragma unroll
            for (int i = 0; i < 8; ++i) {
                int v = i * 8 + rp * 2;
                float2 a = *(const float2*)(vpb + (size_t)v * HD);
                float2 c = *(const float2*)(vpb + (size_t)(v + 1) * HD);
                uint w0 = (uint)bf16rne(a.x) | ((uint)bf16rne(c.x) << 16);
                uint w1 = (uint)bf16rne(a.y) | ((uint)bf16rne(c.y) << 16);
                *(uint*)&vt[h * VSTR + v]       = w0;
                *(uint*)&vt[(h + 1) * VSTR + v] = w1;
            }
        }
        __syncthreads();

        // ---- QK^T: 3-term bf16 split MFMA ----
        floatx4 cf[4];
#pragma unroll
        for (int nb = 0; nb < 4; ++nb) cf[nb] = (floatx4){0.f, 0.f, 0.f, 0.f};
#pragma unroll
        for (int kc = 0; kc < 4; ++kc) {
#pragma unroll
            for (int nb = 0; nb < 4; ++nb) {
                int off = (nb * 16 + r) * KSTR + kc * 32 + qd * 8;
                short8 kh = *(const short8*)&khi[off];
                short8 kl = *(const short8*)&klo[off];
                cf[nb] = __builtin_amdgcn_mfma_f32_16x16x32_bf16(qfh[kc], kh, cf[nb], 0, 0, 0);
                cf[nb] = __builtin_amdgcn_mfma_f32_16x16x32_bf16(qfh[kc], kl, cf[nb], 0, 0, 0);
                cf[nb] = __builtin_amdgcn_mfma_f32_16x16x32_bf16(qfl[kc], kh, cf[nb], 0, 0, 0);
            }
        }

        // ---- online softmax (exp2 domain) ----
        float ts[4][4], p[4][4];
#pragma unroll
        for (int nb = 0; nb < 4; ++nb)
#pragma unroll
            for (int g = 0; g < 4; ++g) ts[nb][g] = cf[nb][g] * SCL2E;

        float tmax[4], tsum[4], alpha[4], lnew[4];
#pragma unroll
        for (int g = 0; g < 4; ++g) {
            float t = fmaxf(fmaxf(ts[0][g], ts[1][g]), fmaxf(ts[2][g], ts[3][g]));
#pragma unroll
            for (int off = 1; off < 16; off <<= 1)
                t = fmaxf(t, __shfl_xor(t, off));
            tmax[g] = t;
            float mn = fmaxf(m2[g], t);
            alpha[g] = __builtin_amdgcn_exp2f(m2[g] - mn);
            m2[g] = mn;
        }
#pragma unroll
        for (int g = 0; g < 4; ++g) {
            float s = 0.f;
#pragma unroll
            for (int nb = 0; nb < 4; ++nb) {
                p[nb][g] = __builtin_amdgcn_exp2f(ts[nb][g] - m2[g]);
                s += p[nb][g];
            }
#pragma unroll
            for (int off = 1; off < 16; off <<= 1)
                s += __shfl_xor(s, off);
            tsum[g] = s;
            lnew[g] = lr[g] * alpha[g] + s;
            lr[g] = lnew[g];
        }

        bool rowneed = false;
#pragma unroll
        for (int g = 0; g < 4; ++g) rowneed |= (tsum[g] > EPS_SKIP * lnew[g]);

        if (__any(rowneed)) {
            // rescale O accumulator (alpha==1 exactly on skipped tiles, so only here)
#pragma unroll
            for (int n = 0; n < 8; ++n)
#pragma unroll
                for (int g = 0; g < 4; ++g) oacc[n][g] *= alpha[g];

            // dropout (threefry) per 16-col block, skipped when block mass negligible
#pragma unroll
            for (int nb = 0; nb < 4; ++nb) {
                bool nbneed = false;
#pragma unroll
                for (int g = 0; g < 4; ++g) nbneed |= (p[nb][g] > EPS_SKIP * lnew[g]);
                if (__any(nbneed)) {
#pragma unroll
                    for (int g = 0; g < 4; ++g) {
                        uint j = (uint)(waveRow0 + qd * 4 + g) * (uint)NV
                               + (uint)(v0 + nb * 16 + r);
                        if (threefry_bits(j) >= KEEP_THRESH) p[nb][g] = 0.f;
                    }
                }
#pragma unroll
                for (int g = 0; g < 4; ++g)
                    pls[wave][(qd * 4 + g) * PSTR + nb * 16 + r] = bf16rne(p[nb][g]);
            }
            __asm__ volatile("s_waitcnt lgkmcnt(0)" ::: "memory");  // own-wave P writes visible

            // ---- PV: O += P * V ----
#pragma unroll
            for (int kc2 = 0; kc2 < 2; ++kc2) {
                short8 pa = *(const short8*)&pls[wave][r * PSTR + kc2 * 32 + qd * 8];
#pragma unroll
                for (int n = 0; n < 8; ++n) {
                    int off = (n * 16 + r) * VSTR + kc2 * 32 + qd * 8;
                    ushort4 u0 = *(const ushort4*)&vt[off];
                    ushort4 u1 = *(const ushort4*)&vt[off + 4];
                    short8 vb;
                    vb[0] = (short)u0.x; vb[1] = (short)u0.y; vb[2] = (short)u0.z; vb[3] = (short)u0.w;
                    vb[4] = (short)u1.x; vb[5] = (short)u1.y; vb[6] = (short)u1.z; vb[7] = (short)u1.w;
                    oacc[n] = __builtin_amdgcn_mfma_f32_16x16x32_bf16(pa, vb, oacc[n], 0, 0, 0);
                }
            }
        }
    }

    // ---- epilogue: out = acc / (0.9 * l) ----
    float inv[4];
#pragma unroll
    for (int g = 0; g < 4; ++g) inv[g] = 1.0f / (0.9f * lr[g]);
#pragma unroll
    for (int n = 0; n < 8; ++n)
#pragma unroll
        for (int g = 0; g < 4; ++g)
            Og[(size_t)(waveRow0 + qd * 4 + g) * HD + n * 16 + r] = oacc[n][g] * inv[g];
}

extern "C" void kernel_launch(void* const* d_in, const int* in_sizes, int n_in,
                              void* d_out, int out_size, void* d_ws, size_t ws_size,
                              hipStream_t stream) {
    (void)in_sizes; (void)n_in; (void)out_size; (void)d_ws; (void)ws_size;
    const float* Qg = (const float*)d_in[0];
    const float* Kg = (const float*)d_in[1];
    const float* Vg = (const float*)d_in[2];
    float* Og = (float*)d_out;
    dim3 grid(NBATCH * NQ / 64);   // 256 blocks x 256 threads: 1 block/CU
    fa_mfma<<<grid, 256, 0, stream>>>(Qg, Kg, Vg, Og);
}

// Round 4
// 247.074 us; speedup vs baseline: 3.5755x; 1.4295x over previous
//
#include <hip/hip_runtime.h>
#include <stdint.h>

// B=4, Q=4096, V=4096, H=128, fp32 in/out
#define NBATCH 4
#define NQ 4096
#define NV 4096
#define HD 128

// SCALE * log2(e): scores scaled into exp2 domain
#define SCL2E ((float)(11.31370849898476 * 1.4426950408889634))

// keep  <=>  bits < 0.9f in fixed point (0.9f = 7549747 * 2^-23)
#define KEEP_THRESH 3865470464u
#define EPS_SKIP 1e-6f

#define PSTR 72    // pls row stride (ushorts)

// --- fast path (prepass + DMA staging) ---
// per (batch,tile) record: [khi 8192 ush][klo 8192 ush][vt 8192 ush] = 48 KB
// chunk = 8 ushorts = 16B.  XOR-swizzled chunk positions (2-way bank = free):
#define CHK_K(v,c) ((((v) * 16) + (((c) ^ (v)) & 15)) * 8)   // v 0..63, c 0..15
#define CHK_V(h,c) ((((h) * 8)  + (((c) ^ (h)) & 7))  * 8)   // h 0..127, c 0..7
#define TILE_USH 24576
#define WS_NEEDED ((size_t)NBATCH * 64 * TILE_USH * 2)       // 12,582,912 B

// --- fallback path constants (round-3 kernel, verified passing) ---
#define KSTR 144
#define VSTR 76

typedef __attribute__((ext_vector_type(8))) short short8;   // 8 bf16 (MFMA A/B frag)
typedef __attribute__((ext_vector_type(4))) float floatx4;  // MFMA C/D frag
typedef unsigned int uint;
typedef unsigned short ushort;
typedef __attribute__((address_space(3))) uint lds_u32;
typedef __attribute__((address_space(1))) const uint glb_u32;

__device__ __forceinline__ ushort bf16rne(float f) {
    uint u = __float_as_uint(f);
    u = (u + 0x7fffu + ((u >> 16) & 1u)) >> 16;
    return (ushort)u;
}
__device__ __forceinline__ float bf2f(ushort h) {
    return __uint_as_float(((uint)h) << 16);
}

__device__ __forceinline__ uint rotl(uint x, int r) { return (x << r) | (x >> (32 - r)); }

// JAX threefry2x32 partitionable path, key=(0,42): bits = y0 ^ y1 of hash of 64-bit counter j
__device__ __forceinline__ uint threefry_bits(uint j) {
    uint x0 = 0u;   // counter hi word (all j < 2^32)
    uint x1 = j;
    const uint k0 = 0u, k1 = 42u, k2 = 0u ^ 42u ^ 0x1BD11BDAu;
    x0 += k0; x1 += k1;
#define TFR4(a,b,c,d) \
    x0 += x1; x1 = rotl(x1, a); x1 ^= x0; \
    x0 += x1; x1 = rotl(x1, b); x1 ^= x0; \
    x0 += x1; x1 = rotl(x1, c); x1 ^= x0; \
    x0 += x1; x1 = rotl(x1, d); x1 ^= x0;
    TFR4(13, 15, 26, 6)
    x0 += k1; x1 += k2 + 1u;
    TFR4(17, 29, 16, 24)
    x0 += k2; x1 += k0 + 2u;
    TFR4(13, 15, 26, 6)
    x0 += k0; x1 += k1 + 3u;
    TFR4(17, 29, 16, 24)
    x0 += k1; x1 += k2 + 4u;
    TFR4(13, 15, 26, 6)
    x0 += k2; x1 += k0 + 5u;
#undef TFR4
    return x0 ^ x1;
}

// ============================ prepass ============================
// grid 256 = 4 batches x 64 tiles; converts K -> bf16 hi/lo chunks and
// V -> transposed bf16 chunks, in the exact linear order the DMA wants.
__global__ __launch_bounds__(256)
void prepass(const float* __restrict__ Kg, const float* __restrict__ Vg,
             ushort* __restrict__ W) {
    const int bb = blockIdx.x >> 6;
    const int t  = blockIdx.x & 63;
    const int v0 = t * 64;
    const size_t kvbase = (size_t)bb * NV * HD;
    ushort* dst = W + ((size_t)bb * 64 + t) * TILE_USH;
    ushort* dkh = dst;
    ushort* dkl = dst + 8192;
    ushort* dvt = dst + 16384;
    const int tid = threadIdx.x;

    // K: 1024 chunks (64 rows x 16 chunk-cols)
#pragma unroll
    for (int i = 0; i < 4; ++i) {
        int lc = i * 256 + tid;
        int v = lc >> 4, c = lc & 15;
        const float* src = Kg + kvbase + (size_t)(v0 + v) * HD + c * 8;
        float x[8];
        *(float4*)&x[0] = *(const float4*)src;
        *(float4*)&x[4] = *(const float4*)(src + 4);
        uint H[4], L[4];
#pragma unroll
        for (int k = 0; k < 4; ++k) {
            ushort h0 = bf16rne(x[2 * k]),     h1 = bf16rne(x[2 * k + 1]);
            ushort l0 = bf16rne(x[2 * k] - bf2f(h0));
            ushort l1 = bf16rne(x[2 * k + 1] - bf2f(h1));
            H[k] = (uint)h0 | ((uint)h1 << 16);
            L[k] = (uint)l0 | ((uint)l1 << 16);
        }
        int pos = CHK_K(v, c);
        *(uint4*)&dkh[pos] = *(uint4*)H;
        *(uint4*)&dkl[pos] = *(uint4*)L;
    }
    // V^T: 1024 chunks (128 h-rows x 8 chunk-cols); column gather, L1-resident
#pragma unroll
    for (int i = 0; i < 4; ++i) {
        int lc = i * 256 + tid;
        int h = lc >> 3, c2 = lc & 7;
        uint Wd[4];
#pragma unroll
        for (int m = 0; m < 8; m += 2) {
            float a = Vg[kvbase + (size_t)(v0 + c2 * 8 + m) * HD + h];
            float b2 = Vg[kvbase + (size_t)(v0 + c2 * 8 + m + 1) * HD + h];
            Wd[m >> 1] = (uint)bf16rne(a) | ((uint)bf16rne(b2) << 16);
        }
        int pos = CHK_V(h, c2);
        *(uint4*)&dvt[pos] = *(uint4*)Wd;
    }
}

// ============================ main (fast path) ============================
// Fragment layouts (gfx950 mfma_f32_16x16x32_bf16, m89/m120-verified):
//   A: lane holds A[m = lane&15][k = (lane>>4)*8 + j]
//   B: lane holds B[k = (lane>>4)*8 + j][n = lane&15]
//   C/D: lane holds D[row = (lane>>4)*4 + reg][col = lane&15]
__global__ __launch_bounds__(256)
void fa_mfma2(const float* __restrict__ Qg, const ushort* __restrict__ Wk,
              float* __restrict__ Og) {
    __shared__ __align__(16) ushort buf[2][TILE_USH];   // 2 x 48 KB
    __shared__ ushort pls[4][16 * PSTR];                // 9.2 KB

    const int tid  = threadIdx.x;
    const int wave = tid >> 6;
    const int lane = tid & 63;
    const int r    = lane & 15;
    const int qd   = lane >> 4;
    const int blockRow0 = blockIdx.x * 64;
    const int b = blockRow0 >> 12;
    const int waveRow0 = blockRow0 + wave * 16;
    const ushort* kvw = Wk + (size_t)b * 64 * TILE_USH;

    // Q -> A-fragments (hi/lo bf16 split), registers
    short8 qfh[4], qfl[4];
    {
        const float* qp = Qg + (size_t)(waveRow0 + r) * HD + qd * 8;
#pragma unroll
        for (int kc = 0; kc < 4; ++kc) {
            float x[8];
            *(float4*)&x[0] = *(const float4*)(qp + kc * 32);
            *(float4*)&x[4] = *(const float4*)(qp + kc * 32 + 4);
#pragma unroll
            for (int j = 0; j < 8; ++j) {
                ushort h = bf16rne(x[j]);
                qfh[kc][j] = (short)h;
                qfl[kc][j] = (short)bf16rne(x[j] - bf2f(h));
            }
        }
    }

    floatx4 oacc[8];
#pragma unroll
    for (int n = 0; n < 8; ++n) oacc[n] = (floatx4){0.f, 0.f, 0.f, 0.f};
    float m2[4] = {-INFINITY, -INFINITY, -INFINITY, -INFINITY};
    float lr[4] = {0.f, 0.f, 0.f, 0.f};

    // async DMA of one 48KB tile record into buf[s]: 3072 chunks, 12 per thread
#define STAGE(tt, ss) do { \
        const ushort* _src = kvw + (size_t)(tt) * TILE_USH; \
        _Pragma("unroll") \
        for (int _i = 0; _i < 12; ++_i) { \
            int _c = _i * 256 + tid; \
            __builtin_amdgcn_global_load_lds((glb_u32*)(_src + _c * 8), \
                (lds_u32*)&buf[ss][(_i * 256 + wave * 64) * 8], 16, 0, 0); \
        } \
    } while (0)

    STAGE(0, 0);

    for (int t = 0; t < 64; ++t) {
        // waits vmcnt(0): tile t's DMA landed; joins: everyone done reading t-1
        __syncthreads();
        if (t + 1 < 64) STAGE(t + 1, (t + 1) & 1);

        const ushort* KH = buf[t & 1];
        const ushort* KL = KH + 8192;
        const ushort* VT = KH + 16384;
        const int v0 = t * 64;

        // ---- QK^T: 3-term bf16-split MFMA ----
        floatx4 cf[4];
#pragma unroll
        for (int nb = 0; nb < 4; ++nb) cf[nb] = (floatx4){0.f, 0.f, 0.f, 0.f};
#pragma unroll
        for (int kc = 0; kc < 4; ++kc) {
#pragma unroll
            for (int nb = 0; nb < 4; ++nb) {
                int ch = CHK_K(nb * 16 + r, kc * 4 + qd);
                short8 kh = *(const short8*)&KH[ch];
                short8 kl = *(const short8*)&KL[ch];
                cf[nb] = __builtin_amdgcn_mfma_f32_16x16x32_bf16(qfh[kc], kh, cf[nb], 0, 0, 0);
                cf[nb] = __builtin_amdgcn_mfma_f32_16x16x32_bf16(qfh[kc], kl, cf[nb], 0, 0, 0);
                cf[nb] = __builtin_amdgcn_mfma_f32_16x16x32_bf16(qfl[kc], kh, cf[nb], 0, 0, 0);
            }
        }

        // ---- online softmax (exp2 domain) ----
        float ts[4][4], p[4][4];
#pragma unroll
        for (int nb = 0; nb < 4; ++nb)
#pragma unroll
            for (int g = 0; g < 4; ++g) ts[nb][g] = cf[nb][g] * SCL2E;

        float tsum[4], alpha[4], lnew[4];
#pragma unroll
        for (int g = 0; g < 4; ++g) {
            float tm = fmaxf(fmaxf(ts[0][g], ts[1][g]), fmaxf(ts[2][g], ts[3][g]));
#pragma unroll
            for (int off = 1; off < 16; off <<= 1)
                tm = fmaxf(tm, __shfl_xor(tm, off));
            float mn = fmaxf(m2[g], tm);
            alpha[g] = __builtin_amdgcn_exp2f(m2[g] - mn);
            m2[g] = mn;
        }
#pragma unroll
        for (int g = 0; g < 4; ++g) {
            float s = 0.f;
#pragma unroll
            for (int nb = 0; nb < 4; ++nb) {
                p[nb][g] = __builtin_amdgcn_exp2f(ts[nb][g] - m2[g]);
                s += p[nb][g];
            }
#pragma unroll
            for (int off = 1; off < 16; off <<= 1)
                s += __shfl_xor(s, off);
            tsum[g] = s;
            lnew[g] = lr[g] * alpha[g] + s;
            lr[g] = lnew[g];
        }

        bool rowneed = false;
#pragma unroll
        for (int g = 0; g < 4; ++g) rowneed |= (tsum[g] > EPS_SKIP * lnew[g]);

        if (__any(rowneed)) {
            // alpha==1 exactly on skipped tiles, so rescale only here
#pragma unroll
            for (int n = 0; n < 8; ++n)
#pragma unroll
                for (int g = 0; g < 4; ++g) oacc[n][g] *= alpha[g];

            // dropout, gated per (nb, g) 64-element granule
#pragma unroll
            for (int nb = 0; nb < 4; ++nb) {
#pragma unroll
                for (int g = 0; g < 4; ++g) {
                    if (__any(p[nb][g] > EPS_SKIP * lnew[g])) {
                        uint j = (uint)(waveRow0 + qd * 4 + g) * (uint)NV
                               + (uint)(v0 + nb * 16 + r);
                        if (threefry_bits(j) >= KEEP_THRESH) p[nb][g] = 0.f;
                    }
                    // bf16 truncation (1 op; ~0.2% downward bias, within budget)
                    pls[wave][(qd * 4 + g) * PSTR + nb * 16 + r] =
                        (ushort)(__float_as_uint(p[nb][g]) >> 16);
                }
            }
            __asm__ volatile("s_waitcnt lgkmcnt(0)" ::: "memory");

            // ---- PV: O += P * V ----
#pragma unroll
            for (int kc2 = 0; kc2 < 2; ++kc2) {
                short8 pa = *(const short8*)&pls[wave][r * PSTR + kc2 * 32 + qd * 8];
#pragma unroll
                for (int n = 0; n < 8; ++n) {
                    short8 vb = *(const short8*)&VT[CHK_V(n * 16 + r, kc2 * 4 + qd)];
                    oacc[n] = __builtin_amdgcn_mfma_f32_16x16x32_bf16(pa, vb, oacc[n], 0, 0, 0);
                }
            }
        }
    }
#undef STAGE

    // epilogue: out = acc / (0.9 * l)
    float inv[4];
#pragma unroll
    for (int g = 0; g < 4; ++g) inv[g] = 1.0f / (0.9f * lr[g]);
#pragma unroll
    for (int n = 0; n < 8; ++n)
#pragma unroll
        for (int g = 0; g < 4; ++g)
            Og[(size_t)(waveRow0 + qd * 4 + g) * HD + n * 16 + r] = oacc[n][g] * inv[g];
}

// ============================ fallback (round-3, verified) ============================
__global__ __launch_bounds__(256)
void fa_mfma(const float* __restrict__ Qg, const float* __restrict__ Kg,
             const float* __restrict__ Vg, float* __restrict__ Og) {
    __shared__ ushort khi[64 * KSTR];
    __shared__ ushort klo[64 * KSTR];
    __shared__ ushort vt[128 * VSTR];
    __shared__ ushort pls[4][16 * PSTR];

    const int tid  = threadIdx.x;
    const int wave = tid >> 6;
    const int lane = tid & 63;
    const int r    = lane & 15;
    const int qd   = lane >> 4;
    const int blockRow0 = blockIdx.x * 64;
    const int b = blockRow0 >> 12;
    const int waveRow0 = blockRow0 + wave * 16;
    const size_t kvbase = (size_t)b * NV * HD;

    short8 qfh[4], qfl[4];
    {
        const float* qp = Qg + (size_t)(waveRow0 + r) * HD + qd * 8;
#pragma unroll
        for (int kc = 0; kc < 4; ++kc) {
            float x[8];
            *(float4*)&x[0] = *(const float4*)(qp + kc * 32);
            *(float4*)&x[4] = *(const float4*)(qp + kc * 32 + 4);
#pragma unroll
            for (int j = 0; j < 8; ++j) {
                ushort h = bf16rne(x[j]);
                ushort l = bf16rne(x[j] - bf2f(h));
                qfh[kc][j] = (short)h;
                qfl[kc][j] = (short)l;
            }
        }
    }

    floatx4 oacc[8];
#pragma unroll
    for (int n = 0; n < 8; ++n) oacc[n] = (floatx4){0.f, 0.f, 0.f, 0.f};
    float m2[4] = {-INFINITY, -INFINITY, -INFINITY, -INFINITY};
    float lr[4] = {0.f, 0.f, 0.f, 0.f};

    for (int v0 = 0; v0 < NV; v0 += 64) {
        __syncthreads();
#pragma unroll
        for (int i = 0; i < 8; ++i) {
            int f = i * 256 + tid;
            int v = f >> 5;
            int h = (f & 31) * 4;
            float4 kv = *(const float4*)(Kg + kvbase + (size_t)(v0 + v) * HD + h);
            ushort4 hh, ll;
            hh.x = bf16rne(kv.x); ll.x = bf16rne(kv.x - bf2f(hh.x));
            hh.y = bf16rne(kv.y); ll.y = bf16rne(kv.y - bf2f(hh.y));
            hh.z = bf16rne(kv.z); ll.z = bf16rne(kv.z - bf2f(hh.z));
            hh.w = bf16rne(kv.w); ll.w = bf16rne(kv.w - bf2f(hh.w));
            *(ushort4*)&khi[v * KSTR + h] = hh;
            *(ushort4*)&klo[v * KSTR + h] = ll;
        }
        {
            int hp = tid & 63, rp = tid >> 6;
            int h = hp * 2;
            const float* vpb = Vg + kvbase + (size_t)v0 * HD + h;
#pragma unroll
            for (int i = 0; i < 8; ++i) {
                int v = i * 8 + rp * 2;
                float2 a = *(const float2*)(vpb + (size_t)v * HD);
                float2 c = *(const float2*)(vpb + (size_t)(v + 1) * HD);
                uint w0 = (uint)bf16rne(a.x) | ((uint)bf16rne(c.x) << 16);
                uint w1 = (uint)bf16rne(a.y) | ((uint)bf16rne(c.y) << 16);
                *(uint*)&vt[h * VSTR + v]       = w0;
                *(uint*)&vt[(h + 1) * VSTR + v] = w1;
            }
        }
        __syncthreads();

        floatx4 cf[4];
#pragma unroll
        for (int nb = 0; nb < 4; ++nb) cf[nb] = (floatx4){0.f, 0.f, 0.f, 0.f};
#pragma unroll
        for (int kc = 0; kc < 4; ++kc) {
#pragma unroll
            for (int nb = 0; nb < 4; ++nb) {
                int off = (nb * 16 + r) * KSTR + kc * 32 + qd * 8;
                short8 kh = *(const short8*)&khi[off];
                short8 kl = *(const short8*)&klo[off];
                cf[nb] = __builtin_amdgcn_mfma_f32_16x16x32_bf16(qfh[kc], kh, cf[nb], 0, 0, 0);
                cf[nb] = __builtin_amdgcn_mfma_f32_16x16x32_bf16(qfh[kc], kl, cf[nb], 0, 0, 0);
                cf[nb] = __builtin_amdgcn_mfma_f32_16x16x32_bf16(qfl[kc], kh, cf[nb], 0, 0, 0);
            }
        }

        float ts[4][4], p[4][4];
#pragma unroll
        for (int nb = 0; nb < 4; ++nb)
#pragma unroll
            for (int g = 0; g < 4; ++g) ts[nb][g] = cf[nb][g] * SCL2E;

        float tsum[4], alpha[4], lnew[4];
#pragma unroll
        for (int g = 0; g < 4; ++g) {
            float tm = fmaxf(fmaxf(ts[0][g], ts[1][g]), fmaxf(ts[2][g], ts[3][g]));
#pragma unroll
            for (int off = 1; off < 16; off <<= 1)
                tm = fmaxf(tm, __shfl_xor(tm, off));
            float mn = fmaxf(m2[g], tm);
            alpha[g] = __builtin_amdgcn_exp2f(m2[g] - mn);
            m2[g] = mn;
        }
#pragma unroll
        for (int g = 0; g < 4; ++g) {
            float s = 0.f;
#pragma unroll
            for (int nb = 0; nb < 4; ++nb) {
                p[nb][g] = __builtin_amdgcn_exp2f(ts[nb][g] - m2[g]);
                s += p[nb][g];
            }
#pragma unroll
            for (int off = 1; off < 16; off <<= 1)
                s += __shfl_xor(s, off);
            tsum[g] = s;
            lnew[g] = lr[g] * alpha[g] + s;
            lr[g] = lnew[g];
        }

        bool rowneed = false;
#pragma unroll
        for (int g = 0; g < 4; ++g) rowneed |= (tsum[g] > 1e-8f * lnew[g]);

        if (__any(rowneed)) {
#pragma unroll
            for (int n = 0; n < 8; ++n)
#pragma unroll
                for (int g = 0; g < 4; ++g) oacc[n][g] *= alpha[g];

#pragma unroll
            for (int nb = 0; nb < 4; ++nb) {
                bool nbneed = false;
#pragma unroll
                for (int g = 0; g < 4; ++g) nbneed |= (p[nb][g] > 1e-8f * lnew[g]);
                if (__any(nbneed)) {
#pragma unroll
                    for (int g = 0; g < 4; ++g) {
                        uint j = (uint)(waveRow0 + qd * 4 + g) * (uint)NV
                               + (uint)(v0 + nb * 16 + r);
                        if (threefry_bits(j) >= KEEP_THRESH) p[nb][g] = 0.f;
                    }
                }
#pragma unroll
                for (int g = 0; g < 4; ++g)
                    pls[wave][(qd * 4 + g) * PSTR + nb * 16 + r] = bf16rne(p[nb][g]);
            }
            __asm__ volatile("s_waitcnt lgkmcnt(0)" ::: "memory");

#pragma unroll
            for (int kc2 = 0; kc2 < 2; ++kc2) {
                short8 pa = *(const short8*)&pls[wave][r * PSTR + kc2 * 32 + qd * 8];
#pragma unroll
                for (int n = 0; n < 8; ++n) {
                    int off = (n * 16 + r) * VSTR + kc2 * 32 + qd * 8;
                    ushort4 u0 = *(const ushort4*)&vt[off];
                    ushort4 u1 = *(const ushort4*)&vt[off + 4];
                    short8 vb;
                    vb[0] = (short)u0.x; vb[1] = (short)u0.y; vb[2] = (short)u0.z; vb[3] = (short)u0.w;
                    vb[4] = (short)u1.x; vb[5] = (short)u1.y; vb[6] = (short)u1.z; vb[7] = (short)u1.w;
                    oacc[n] = __builtin_amdgcn_mfma_f32_16x16x32_bf16(pa, vb, oacc[n], 0, 0, 0);
                }
            }
        }
    }

    float inv[4];
#pragma unroll
    for (int g = 0; g < 4; ++g) inv[g] = 1.0f / (0.9f * lr[g]);
#pragma unroll
    for (int n = 0; n < 8; ++n)
#pragma unroll
        for (int g = 0; g < 4; ++g)
            Og[(size_t)(waveRow0 + qd * 4 + g) * HD + n * 16 + r] = oacc[n][g] * inv[g];
}

extern "C" void kernel_launch(void* const* d_in, const int* in_sizes, int n_in,
                              void* d_out, int out_size, void* d_ws, size_t ws_size,
                              hipStream_t stream) {
    (void)in_sizes; (void)n_in; (void)out_size;
    const float* Qg = (const float*)d_in[0];
    const float* Kg = (const float*)d_in[1];
    const float* Vg = (const float*)d_in[2];
    float* Og = (float*)d_out;
    if (ws_size >= WS_NEEDED) {
        prepass<<<dim3(256), 256, 0, stream>>>(Kg, Vg, (ushort*)d_ws);
        fa_mfma2<<<dim3(NBATCH * NQ / 64), 256, 0, stream>>>(Qg, (const ushort*)d_ws, Og);
    } else {
        fa_mfma<<<dim3(NBATCH * NQ / 64), 256, 0, stream>>>(Qg, Kg, Vg, Og);
    }
}

// Round 5
// 238.028 us; speedup vs baseline: 3.7114x; 1.0380x over previous
//
#include <hip/hip_runtime.h>
#include <stdint.h>

// B=4, Q=4096, V=4096, H=128, fp32 in/out
#define NBATCH 4
#define NQ 4096
#define NV 4096
#define HD 128

// SCALE * log2(e): scores scaled into exp2 domain
#define SCL2E ((float)(11.31370849898476 * 1.4426950408889634))

// keep  <=>  bits < 0.9f in fixed point (0.9f = 7549747 * 2^-23)
#define KEEP_THRESH 3865470464u
#define EPS_SKIP 1e-6f

// --- fast path (prepass + DMA staging) ---
// per (batch,tile) record: [khi 8192 ush][klo 8192 ush][vt 8192 ush] = 48 KB
// chunk = 8 ushorts = 16B.  XOR-swizzled chunk positions (2-way bank = free):
#define CHK_K(v,c) ((((v) * 16) + (((c) ^ (v)) & 15)) * 8)   // v 0..63, c 0..15
#define CHK_V(h,c) ((((h) * 8)  + (((c) ^ (h)) & 7))  * 8)   // h 0..127, c 0..7
#define TILE_USH 24576
#define WS_NEEDED ((size_t)NBATCH * 64 * TILE_USH * 2)       // 12,582,912 B

#define PSTR2 40   // pls row stride (ushorts): 16 rows x 32 cols + pad, 16B-aligned
#define VLSTR 140  // prepass LDS v-tile stride (ushorts): 8B-aligned rows

// --- fallback path constants (round-3 kernel, verified passing) ---
#define KSTR 144
#define VSTR 76
#define PSTR 72

typedef __attribute__((ext_vector_type(8))) short short8;   // 8 bf16 (MFMA A/B frag)
typedef __attribute__((ext_vector_type(4))) float floatx4;  // MFMA C/D frag
typedef unsigned int uint;
typedef unsigned short ushort;
typedef __attribute__((address_space(3))) uint lds_u32;
typedef __attribute__((address_space(1))) const uint glb_u32;

__device__ __forceinline__ ushort bf16rne(float f) {
    uint u = __float_as_uint(f);
    u = (u + 0x7fffu + ((u >> 16) & 1u)) >> 16;
    return (ushort)u;
}
__device__ __forceinline__ float bf2f(ushort h) {
    return __uint_as_float(((uint)h) << 16);
}

__device__ __forceinline__ uint rotl(uint x, int r) { return (x << r) | (x >> (32 - r)); }

// JAX threefry2x32 partitionable path, key=(0,42): bits = y0 ^ y1 of hash of 64-bit counter j
__device__ __forceinline__ uint threefry_bits(uint j) {
    uint x0 = 0u;   // counter hi word (all j < 2^32)
    uint x1 = j;
    const uint k0 = 0u, k1 = 42u, k2 = 0u ^ 42u ^ 0x1BD11BDAu;
    x0 += k0; x1 += k1;
#define TFR4(a,b,c,d) \
    x0 += x1; x1 = rotl(x1, a); x1 ^= x0; \
    x0 += x1; x1 = rotl(x1, b); x1 ^= x0; \
    x0 += x1; x1 = rotl(x1, c); x1 ^= x0; \
    x0 += x1; x1 = rotl(x1, d); x1 ^= x0;
    TFR4(13, 15, 26, 6)
    x0 += k1; x1 += k2 + 1u;
    TFR4(17, 29, 16, 24)
    x0 += k2; x1 += k0 + 2u;
    TFR4(13, 15, 26, 6)
    x0 += k0; x1 += k1 + 3u;
    TFR4(17, 29, 16, 24)
    x0 += k1; x1 += k2 + 4u;
    TFR4(13, 15, 26, 6)
    x0 += k2; x1 += k0 + 5u;
#undef TFR4
    return x0 ^ x1;
}

// ============================ prepass ============================
// grid 256 = 4 batches x 64 tiles. K: coalesced convert. V: coalesced read ->
// LDS bf16 tile -> transposed coalesced chunk writes (fixes the 58us gather).
__global__ __launch_bounds__(256)
void prepass(const float* __restrict__ Kg, const float* __restrict__ Vg,
             ushort* __restrict__ W) {
    __shared__ ushort vls[64 * VLSTR];   // 17.9 KB
    const int bb = blockIdx.x >> 6;
    const int t  = blockIdx.x & 63;
    const int v0 = t * 64;
    const size_t kvbase = (size_t)bb * NV * HD;
    ushort* dst = W + ((size_t)bb * 64 + t) * TILE_USH;
    ushort* dkh = dst;
    ushort* dkl = dst + 8192;
    ushort* dvt = dst + 16384;
    const int tid = threadIdx.x;

    // K: 1024 chunks (64 rows x 16 chunk-cols), coalesced both sides
#pragma unroll
    for (int i = 0; i < 4; ++i) {
        int lc = i * 256 + tid;
        int v = lc >> 4, c = lc & 15;
        const float* src = Kg + kvbase + (size_t)(v0 + v) * HD + c * 8;
        float x[8];
        *(float4*)&x[0] = *(const float4*)src;
        *(float4*)&x[4] = *(const float4*)(src + 4);
        uint H[4], L[4];
#pragma unroll
        for (int k = 0; k < 4; ++k) {
            ushort h0 = bf16rne(x[2 * k]),     h1 = bf16rne(x[2 * k + 1]);
            ushort l0 = bf16rne(x[2 * k] - bf2f(h0));
            ushort l1 = bf16rne(x[2 * k + 1] - bf2f(h1));
            H[k] = (uint)h0 | ((uint)h1 << 16);
            L[k] = (uint)l0 | ((uint)l1 << 16);
        }
        int pos = CHK_K(v, c);
        *(uint4*)&dkh[pos] = *(uint4*)H;
        *(uint4*)&dkl[pos] = *(uint4*)L;
    }

    // V phase A: coalesced float4 row reads -> bf16 LDS tile [v][h]
#pragma unroll
    for (int i = 0; i < 8; ++i) {
        int idx = i * 256 + tid;
        int v = idx >> 5, hq = idx & 31;
        float4 a = *(const float4*)(Vg + kvbase + (size_t)(v0 + v) * HD + hq * 4);
        uint w0 = (uint)bf16rne(a.x) | ((uint)bf16rne(a.y) << 16);
        uint w1 = (uint)bf16rne(a.z) | ((uint)bf16rne(a.w) << 16);
        uint2 p; p.x = w0; p.y = w1;
        *(uint2*)&vls[v * VLSTR + hq * 4] = p;
    }
    __syncthreads();
    // V phase B: read transposed from LDS, write chunks in OUTPUT order (coalesced)
#pragma unroll
    for (int i = 0; i < 4; ++i) {
        int oc = i * 256 + tid;            // output chunk index
        int h = oc >> 3, swz = oc & 7;
        int c2 = (swz ^ h) & 7;            // source chunk col so CHK_V(h,c2)==oc*8
        uint Wd[4];
#pragma unroll
        for (int m = 0; m < 8; m += 2) {
            ushort a  = vls[(c2 * 8 + m) * VLSTR + h];
            ushort b2 = vls[(c2 * 8 + m + 1) * VLSTR + h];
            Wd[m >> 1] = (uint)a | ((uint)b2 << 16);
        }
        *(uint4*)&dvt[oc * 8] = *(uint4*)Wd;
    }
}

// ============================ main (fast path) ============================
// 512 threads = 8 waves: wave = rg*2 + cw; rg = row-group (16 q rows),
// cw = column half (32 of the 64 tile cols). Split-softmax merge per tile.
// Fragment layouts (gfx950 mfma_f32_16x16x32_bf16, m89/m120-verified):
//   A: lane holds A[m = lane&15][k = (lane>>4)*8 + j]
//   B: lane holds B[k = (lane>>4)*8 + j][n = lane&15]
//   C/D: lane holds D[row = (lane>>4)*4 + reg][col = lane&15]
__global__ __launch_bounds__(512)
void fa_mfma3(const float* __restrict__ Qg, const ushort* __restrict__ Wk,
              float* __restrict__ Og) {
    __shared__ __align__(16) ushort buf[2][TILE_USH];   // 96 KB
    __shared__ ushort pls[8][16 * PSTR2];               // 10.2 KB
    __shared__ float mrow[8][32];                       // (m_part,s_part) x 16 rows/wave

    const int tid  = threadIdx.x;
    const int wave = tid >> 6;
    const int lane = tid & 63;
    const int r    = lane & 15;
    const int qd   = lane >> 4;
    const int rg   = wave >> 1;
    const int cw   = wave & 1;
    const int blockRow0 = blockIdx.x * 64;
    const int b = blockRow0 >> 12;
    const int waveRow0 = blockRow0 + rg * 16;
    const ushort* kvw = Wk + (size_t)b * 64 * TILE_USH;

    // Q -> A-fragments (hi/lo bf16 split), registers (pairs load duplicately, L1-hit)
    short8 qfh[4], qfl[4];
    {
        const float* qp = Qg + (size_t)(waveRow0 + r) * HD + qd * 8;
#pragma unroll
        for (int kc = 0; kc < 4; ++kc) {
            float x[8];
            *(float4*)&x[0] = *(const float4*)(qp + kc * 32);
            *(float4*)&x[4] = *(const float4*)(qp + kc * 32 + 4);
#pragma unroll
            for (int j = 0; j < 8; ++j) {
                ushort h = bf16rne(x[j]);
                qfh[kc][j] = (short)h;
                qfl[kc][j] = (short)bf16rne(x[j] - bf2f(h));
            }
        }
    }

    floatx4 oacc[8];
#pragma unroll
    for (int n = 0; n < 8; ++n) oacc[n] = (floatx4){0.f, 0.f, 0.f, 0.f};
    float m2[4] = {-INFINITY, -INFINITY, -INFINITY, -INFINITY};
    float lr[4] = {0.f, 0.f, 0.f, 0.f};

    // async DMA of one 48KB tile record: 3072 chunks, 6 per thread
#define STAGE(tt, ss) do { \
        const ushort* _src = kvw + (size_t)(tt) * TILE_USH; \
        _Pragma("unroll") \
        for (int _i = 0; _i < 6; ++_i) { \
            int _c = _i * 512 + tid; \
            __builtin_amdgcn_global_load_lds((glb_u32*)(_src + _c * 8), \
                (lds_u32*)&buf[ss][(_i * 512 + wave * 64) * 8], 16, 0, 0); \
        } \
    } while (0)

    STAGE(0, 0);

    for (int t = 0; t < 64; ++t) {
        __syncthreads();   // drains DMA(t) [vmcnt(0)]; all waves done with tile t-1

        const ushort* KH = buf[t & 1];
        const ushort* KL = KH + 8192;
        const ushort* VT = KH + 16384;
        const int v0 = t * 64;

        // ---- QK^T over this wave's 32 cols: 3-term bf16-split MFMA ----
        floatx4 cf[2];
        cf[0] = (floatx4){0.f, 0.f, 0.f, 0.f};
        cf[1] = (floatx4){0.f, 0.f, 0.f, 0.f};
#pragma unroll
        for (int kc = 0; kc < 4; ++kc) {
#pragma unroll
            for (int nb = 0; nb < 2; ++nb) {
                int ch = CHK_K(cw * 32 + nb * 16 + r, kc * 4 + qd);
                short8 kh = *(const short8*)&KH[ch];
                short8 kl = *(const short8*)&KL[ch];
                cf[nb] = __builtin_amdgcn_mfma_f32_16x16x32_bf16(qfh[kc], kh, cf[nb], 0, 0, 0);
                cf[nb] = __builtin_amdgcn_mfma_f32_16x16x32_bf16(qfh[kc], kl, cf[nb], 0, 0, 0);
                cf[nb] = __builtin_amdgcn_mfma_f32_16x16x32_bf16(qfl[kc], kh, cf[nb], 0, 0, 0);
            }
        }

        // ---- local softmax partials (per row = qd*4+g, over 32 cols) ----
        float ts[2][4], pp[2][4], tm[4], sp[4];
#pragma unroll
        for (int nb = 0; nb < 2; ++nb)
#pragma unroll
            for (int g = 0; g < 4; ++g) ts[nb][g] = cf[nb][g] * SCL2E;
#pragma unroll
        for (int g = 0; g < 4; ++g) {
            float tmx = fmaxf(ts[0][g], ts[1][g]);
#pragma unroll
            for (int off = 1; off < 16; off <<= 1)
                tmx = fmaxf(tmx, __shfl_xor(tmx, off));
            tm[g] = tmx;
            float s = 0.f;
#pragma unroll
            for (int nb = 0; nb < 2; ++nb) {
                pp[nb][g] = __builtin_amdgcn_exp2f(ts[nb][g] - tmx);
                s += pp[nb][g];
            }
#pragma unroll
            for (int off = 1; off < 16; off <<= 1)
                s += __shfl_xor(s, off);
            sp[g] = s;
        }
        if (r == 0) {
#pragma unroll
            for (int g = 0; g < 4; ++g) {
                mrow[wave][(qd * 4 + g) * 2]     = tm[g];
                mrow[wave][(qd * 4 + g) * 2 + 1] = sp[g];
            }
        }
        __syncthreads();   // merge partials visible (no outstanding vmem -> cheap)

        if (t + 1 < 64) STAGE(t + 1, (t + 1) & 1);   // overlaps softmax/dropout/PV

        // ---- pair merge + online update (both waves compute identically) ----
        float alpha[4], beta[4];
        bool rowneed = false;
#pragma unroll
        for (int g = 0; g < 4; ++g) {
            float mo = mrow[wave ^ 1][(qd * 4 + g) * 2];
            float so = mrow[wave ^ 1][(qd * 4 + g) * 2 + 1];
            float mt = fmaxf(tm[g], mo);
            float mn = fmaxf(m2[g], mt);
            alpha[g] = __builtin_amdgcn_exp2f(m2[g] - mn);
            beta[g]  = __builtin_amdgcn_exp2f(tm[g] - mn);
            float tsum = sp[g] * beta[g] + so * __builtin_amdgcn_exp2f(mo - mn);
            float lnew = lr[g] * alpha[g] + tsum;
            lr[g] = lnew;
            m2[g] = mn;
            rowneed |= (tsum > EPS_SKIP * lnew);
        }

        if (__any(rowneed)) {
            // alpha==1 exactly on skipped tiles, so rescale only here
#pragma unroll
            for (int n = 0; n < 8; ++n)
#pragma unroll
                for (int g = 0; g < 4; ++g) oacc[n][g] *= alpha[g];

            // dropout, gated per (nb, g) granule (4 rows x 16 cols)
#pragma unroll
            for (int nb = 0; nb < 2; ++nb) {
#pragma unroll
                for (int g = 0; g < 4; ++g) {
                    float pf = pp[nb][g] * beta[g];
                    if (__any(pf > EPS_SKIP * lr[g])) {
                        uint j = (uint)(waveRow0 + qd * 4 + g) * (uint)NV
                               + (uint)(v0 + cw * 32 + nb * 16 + r);
                        if (threefry_bits(j) >= KEEP_THRESH) pf = 0.f;
                    }
                    // bf16 truncation (1 op; ~0.2% downward bias, within budget)
                    pls[wave][(qd * 4 + g) * PSTR2 + nb * 16 + r] =
                        (ushort)(__float_as_uint(pf) >> 16);
                }
            }
            __asm__ volatile("s_waitcnt lgkmcnt(0)" ::: "memory");  // own-wave P visible

            // ---- PV over this wave's 32 v's: one K=32 MFMA per n ----
            short8 pa = *(const short8*)&pls[wave][r * PSTR2 + qd * 8];
#pragma unroll
            for (int n = 0; n < 8; ++n) {
                short8 vb = *(const short8*)&VT[CHK_V(n * 16 + r, cw * 4 + qd)];
                oacc[n] = __builtin_amdgcn_mfma_f32_16x16x32_bf16(pa, vb, oacc[n], 0, 0, 0);
            }
        }
    }
#undef STAGE

    // ---- epilogue: sum wave-pair partial O, normalize, store ----
    // buf[0] reuse is safe: disjoint from buf[1] (tile 63's data)
    float* ob = (float*)&buf[0][0];
    if (cw == 1) {
#pragma unroll
        for (int n = 0; n < 8; ++n)
#pragma unroll
            for (int g = 0; g < 4; ++g)
                ob[rg * 2048 + (qd * 4 + g) * 128 + n * 16 + r] = oacc[n][g];
    }
    __syncthreads();
    if (cw == 0) {
        float inv[4];
#pragma unroll
        for (int g = 0; g < 4; ++g) inv[g] = 1.0f / (0.9f * lr[g]);
#pragma unroll
        for (int n = 0; n < 8; ++n)
#pragma unroll
            for (int g = 0; g < 4; ++g) {
                float o = oacc[n][g] + ob[rg * 2048 + (qd * 4 + g) * 128 + n * 16 + r];
                Og[(size_t)(waveRow0 + qd * 4 + g) * HD + n * 16 + r] = o * inv[g];
            }
    }
}

// ============================ fallback (round-3, verified) ============================
__global__ __launch_bounds__(256)
void fa_mfma(const float* __restrict__ Qg, const float* __restrict__ Kg,
             const float* __restrict__ Vg, float* __restrict__ Og) {
    __shared__ ushort khi[64 * KSTR];
    __shared__ ushort klo[64 * KSTR];
    __shared__ ushort vt[128 * VSTR];
    __shared__ ushort plsf[4][16 * PSTR];

    const int tid  = threadIdx.x;
    const int wave = tid >> 6;
    const int lane = tid & 63;
    const int r    = lane & 15;
    const int qd   = lane >> 4;
    const int blockRow0 = blockIdx.x * 64;
    const int b = blockRow0 >> 12;
    const int waveRow0 = blockRow0 + wave * 16;
    const size_t kvbase = (size_t)b * NV * HD;

    short8 qfh[4], qfl[4];
    {
        const float* qp = Qg + (size_t)(waveRow0 + r) * HD + qd * 8;
#pragma unroll
        for (int kc = 0; kc < 4; ++kc) {
            float x[8];
            *(float4*)&x[0] = *(const float4*)(qp + kc * 32);
            *(float4*)&x[4] = *(const float4*)(qp + kc * 32 + 4);
#pragma unroll
            for (int j = 0; j < 8; ++j) {
                ushort h = bf16rne(x[j]);
                qfh[kc][j] = (short)h;
                qfl[kc][j] = (short)bf16rne(x[j] - bf2f(h));
            }
        }
    }

    floatx4 oacc[8];
#pragma unroll
    for (int n = 0; n < 8; ++n) oacc[n] = (floatx4){0.f, 0.f, 0.f, 0.f};
    float m2[4] = {-INFINITY, -INFINITY, -INFINITY, -INFINITY};
    float lr[4] = {0.f, 0.f, 0.f, 0.f};

    for (int v0 = 0; v0 < NV; v0 += 64) {
        __syncthreads();
#pragma unroll
        for (int i = 0; i < 8; ++i) {
            int f = i * 256 + tid;
            int v = f >> 5;
            int h = (f & 31) * 4;
            float4 kv = *(const float4*)(Kg + kvbase + (size_t)(v0 + v) * HD + h);
            ushort4 hh, ll;
            hh.x = bf16rne(kv.x); ll.x = bf16rne(kv.x - bf2f(hh.x));
            hh.y = bf16rne(kv.y); ll.y = bf16rne(kv.y - bf2f(hh.y));
            hh.z = bf16rne(kv.z); ll.z = bf16rne(kv.z - bf2f(hh.z));
            hh.w = bf16rne(kv.w); ll.w = bf16rne(kv.w - bf2f(hh.w));
            *(ushort4*)&khi[v * KSTR + h] = hh;
            *(ushort4*)&klo[v * KSTR + h] = ll;
        }
        {
            int hp = tid & 63, rp = tid >> 6;
            int h = hp * 2;
            const float* vpb = Vg + kvbase + (size_t)v0 * HD + h;
#pragma unroll
            for (int i = 0; i < 8; ++i) {
                int v = i * 8 + rp * 2;
                float2 a = *(const float2*)(vpb + (size_t)v * HD);
                float2 c = *(const float2*)(vpb + (size_t)(v + 1) * HD);
                uint w0 = (uint)bf16rne(a.x) | ((uint)bf16rne(c.x) << 16);
                uint w1 = (uint)bf16rne(a.y) | ((uint)bf16rne(c.y) << 16);
                *(uint*)&vt[h * VSTR + v]       = w0;
                *(uint*)&vt[(h + 1) * VSTR + v] = w1;
            }
        }
        __syncthreads();

        floatx4 cf[4];
#pragma unroll
        for (int nb = 0; nb < 4; ++nb) cf[nb] = (floatx4){0.f, 0.f, 0.f, 0.f};
#pragma unroll
        for (int kc = 0; kc < 4; ++kc) {
#pragma unroll
            for (int nb = 0; nb < 4; ++nb) {
                int off = (nb * 16 + r) * KSTR + kc * 32 + qd * 8;
                short8 kh = *(const short8*)&khi[off];
                short8 kl = *(const short8*)&klo[off];
                cf[nb] = __builtin_amdgcn_mfma_f32_16x16x32_bf16(qfh[kc], kh, cf[nb], 0, 0, 0);
                cf[nb] = __builtin_amdgcn_mfma_f32_16x16x32_bf16(qfh[kc], kl, cf[nb], 0, 0, 0);
                cf[nb] = __builtin_amdgcn_mfma_f32_16x16x32_bf16(qfl[kc], kh, cf[nb], 0, 0, 0);
            }
        }

        float ts[4][4], p[4][4];
#pragma unroll
        for (int nb = 0; nb < 4; ++nb)
#pragma unroll
            for (int g = 0; g < 4; ++g) ts[nb][g] = cf[nb][g] * SCL2E;

        float tsum[4], alpha[4], lnew[4];
#pragma unroll
        for (int g = 0; g < 4; ++g) {
            float tmx = fmaxf(fmaxf(ts[0][g], ts[1][g]), fmaxf(ts[2][g], ts[3][g]));
#pragma unroll
            for (int off = 1; off < 16; off <<= 1)
                tmx = fmaxf(tmx, __shfl_xor(tmx, off));
            float mn = fmaxf(m2[g], tmx);
            alpha[g] = __builtin_amdgcn_exp2f(m2[g] - mn);
            m2[g] = mn;
        }
#pragma unroll
        for (int g = 0; g < 4; ++g) {
            float s = 0.f;
#pragma unroll
            for (int nb = 0; nb < 4; ++nb) {
                p[nb][g] = __builtin_amdgcn_exp2f(ts[nb][g] - m2[g]);
                s += p[nb][g];
            }
#pragma unroll
            for (int off = 1; off < 16; off <<= 1)
                s += __shfl_xor(s, off);
            tsum[g] = s;
            lnew[g] = lr[g] * alpha[g] + s;
            lr[g] = lnew[g];
        }

        bool rowneed = false;
#pragma unroll
        for (int g = 0; g < 4; ++g) rowneed |= (tsum[g] > 1e-8f * lnew[g]);

        if (__any(rowneed)) {
#pragma unroll
            for (int n = 0; n < 8; ++n)
#pragma unroll
                for (int g = 0; g < 4; ++g) oacc[n][g] *= alpha[g];

#pragma unroll
            for (int nb = 0; nb < 4; ++nb) {
                bool nbneed = false;
#pragma unroll
                for (int g = 0; g < 4; ++g) nbneed |= (p[nb][g] > 1e-8f * lnew[g]);
                if (__any(nbneed)) {
#pragma unroll
                    for (int g = 0; g < 4; ++g) {
                        uint j = (uint)(waveRow0 + qd * 4 + g) * (uint)NV
                               + (uint)(v0 + nb * 16 + r);
                        if (threefry_bits(j) >= KEEP_THRESH) p[nb][g] = 0.f;
                    }
                }
#pragma unroll
                for (int g = 0; g < 4; ++g)
                    plsf[wave][(qd * 4 + g) * PSTR + nb * 16 + r] = bf16rne(p[nb][g]);
            }
            __asm__ volatile("s_waitcnt lgkmcnt(0)" ::: "memory");

#pragma unroll
            for (int kc2 = 0; kc2 < 2; ++kc2) {
                short8 pa = *(const short8*)&plsf[wave][r * PSTR + kc2 * 32 + qd * 8];
#pragma unroll
                for (int n = 0; n < 8; ++n) {
                    int off = (n * 16 + r) * VSTR + kc2 * 32 + qd * 8;
                    ushort4 u0 = *(const ushort4*)&vt[off];
                    ushort4 u1 = *(const ushort4*)&vt[off + 4];
                    short8 vb;
                    vb[0] = (short)u0.x; vb[1] = (short)u0.y; vb[2] = (short)u0.z; vb[3] = (short)u0.w;
                    vb[4] = (short)u1.x; vb[5] = (short)u1.y; vb[6] = (short)u1.z; vb[7] = (short)u1.w;
                    oacc[n] = __builtin_amdgcn_mfma_f32_16x16x32_bf16(pa, vb, oacc[n], 0, 0, 0);
                }
            }
        }
    }

    float inv[4];
#pragma unroll
    for (int g = 0; g < 4; ++g) inv[g] = 1.0f / (0.9f * lr[g]);
#pragma unroll
    for (int n = 0; n < 8; ++n)
#pragma unroll
        for (int g = 0; g < 4; ++g)
            Og[(size_t)(waveRow0 + qd * 4 + g) * HD + n * 16 + r] = oacc[n][g] * inv[g];
}

extern "C" void kernel_launch(void* const* d_in, const int* in_sizes, int n_in,
                              void* d_out, int out_size, void* d_ws, size_t ws_size,
                              hipStream_t stream) {
    (void)in_sizes; (void)n_in; (void)out_size;
    const float* Qg = (const float*)d_in[0];
    const float* Kg = (const float*)d_in[1];
    const float* Vg = (const float*)d_in[2];
    float* Og = (float*)d_out;
    if (ws_size >= WS_NEEDED) {
        prepass<<<dim3(256), 256, 0, stream>>>(Kg, Vg, (ushort*)d_ws);
        fa_mfma3<<<dim3(NBATCH * NQ / 64), 512, 0, stream>>>(Qg, (const ushort*)d_ws, Og);
    } else {
        fa_mfma<<<dim3(NBATCH * NQ / 64), 256, 0, stream>>>(Qg, Kg, Vg, Og);
    }
}

// Round 6
// 236.580 us; speedup vs baseline: 3.7341x; 1.0061x over previous
//
#include <hip/hip_runtime.h>
#include <stdint.h>

// B=4, Q=4096, V=4096, H=128, fp32 in/out
#define NBATCH 4
#define NQ 4096
#define NV 4096
#define HD 128

// SCALE * log2(e): scores scaled into exp2 domain
#define SCL2E ((float)(11.31370849898476 * 1.4426950408889634))

// keep  <=>  bits < 0.9f in fixed point (0.9f = 7549747 * 2^-23)
#define KEEP_THRESH 3865470464u
#define EPS_SKIP 1e-6f

// --- ws layout (prepass output) ---
// per (batch,tile) record: [khi 8192 ush][klo 8192 ush][vt 8192 ush] = 48 KB
// chunk = 8 ushorts = 16B.  XOR-swizzled chunk positions (2-way bank = free):
#define CHK_K(v,c) ((((v) * 16) + (((c) ^ (v)) & 15)) * 8)   // v 0..63, c 0..15
#define CHK_V(h,c) ((((h) * 8)  + (((c) ^ (h)) & 7))  * 8)   // h 0..127, c 0..7
#define TILE_USH 24576
#define WS_NEEDED ((size_t)NBATCH * 64 * TILE_USH * 2)       // 12,582,912 B

#define PSTR 72    // pls row stride (ushorts): 2-way banks on b128 reads (free)
#define VLSTR 142  // prepass LDS v-tile stride (ushorts)

// --- fallback path constants (round-3 kernel, verified passing) ---
#define KSTR 144
#define VSTR 76

typedef __attribute__((ext_vector_type(8))) short short8;   // 8 bf16 (MFMA A/B frag)
typedef __attribute__((ext_vector_type(4))) float floatx4;  // MFMA C/D frag
typedef unsigned int uint;
typedef unsigned short ushort;
typedef __attribute__((address_space(3))) uint lds_u32;
typedef __attribute__((address_space(1))) const uint glb_u32;

__device__ __forceinline__ ushort bf16rne(float f) {
    uint u = __float_as_uint(f);
    u = (u + 0x7fffu + ((u >> 16) & 1u)) >> 16;
    return (ushort)u;
}
__device__ __forceinline__ float bf2f(ushort h) {
    return __uint_as_float(((uint)h) << 16);
}

// ---- DPP 16-lane reductions (zero DS-pipe; lanes grouped by row = lane>>4) ----
// quad_perm(1,0,3,2)=0xB1 (xor1), quad_perm(2,3,0,1)=0x4E (xor2),
// row_half_mirror=0x141 (xor7 == xor4 once quads uniform),
// row_mirror=0x140 (xor15 == xor8 once halves uniform)
template <int CTRL>
__device__ __forceinline__ float dppmov(float x) {
    return __int_as_float(__builtin_amdgcn_update_dpp(
        0, __float_as_int(x), CTRL, 0xF, 0xF, true));
}
__device__ __forceinline__ float row_max16(float x) {
    x = fmaxf(x, dppmov<0xB1>(x));
    x = fmaxf(x, dppmov<0x4E>(x));
    x = fmaxf(x, dppmov<0x141>(x));
    x = fmaxf(x, dppmov<0x140>(x));
    return x;
}
__device__ __forceinline__ float row_sum16(float x) {
    x += dppmov<0xB1>(x);
    x += dppmov<0x4E>(x);
    x += dppmov<0x141>(x);
    x += dppmov<0x140>(x);
    return x;
}

__device__ __forceinline__ uint rotl(uint x, int r) { return (x << r) | (x >> (32 - r)); }

// JAX threefry2x32 partitionable path, key=(0,42): bits = y0 ^ y1 of hash of 64-bit counter j
__device__ __forceinline__ uint threefry_bits(uint j) {
    uint x0 = 0u;   // counter hi word (all j < 2^32)
    uint x1 = j;
    const uint k0 = 0u, k1 = 42u, k2 = 0u ^ 42u ^ 0x1BD11BDAu;
    x0 += k0; x1 += k1;
#define TFR4(a,b,c,d) \
    x0 += x1; x1 = rotl(x1, a); x1 ^= x0; \
    x0 += x1; x1 = rotl(x1, b); x1 ^= x0; \
    x0 += x1; x1 = rotl(x1, c); x1 ^= x0; \
    x0 += x1; x1 = rotl(x1, d); x1 ^= x0;
    TFR4(13, 15, 26, 6)
    x0 += k1; x1 += k2 + 1u;
    TFR4(17, 29, 16, 24)
    x0 += k2; x1 += k0 + 2u;
    TFR4(13, 15, 26, 6)
    x0 += k0; x1 += k1 + 3u;
    TFR4(17, 29, 16, 24)
    x0 += k1; x1 += k2 + 4u;
    TFR4(13, 15, 26, 6)
    x0 += k2; x1 += k0 + 5u;
#undef TFR4
    return x0 ^ x1;
}

// ============================ prepass ============================
__global__ __launch_bounds__(256)
void prepass(const float* __restrict__ Kg, const float* __restrict__ Vg,
             ushort* __restrict__ W) {
    __shared__ ushort vls[64 * VLSTR];
    const int bb = blockIdx.x >> 6;
    const int t  = blockIdx.x & 63;
    const int v0 = t * 64;
    const size_t kvbase = (size_t)bb * NV * HD;
    ushort* dst = W + ((size_t)bb * 64 + t) * TILE_USH;
    ushort* dkh = dst;
    ushort* dkl = dst + 8192;
    ushort* dvt = dst + 16384;
    const int tid = threadIdx.x;

    // K: 1024 chunks (64 rows x 16 chunk-cols), coalesced both sides
#pragma unroll
    for (int i = 0; i < 4; ++i) {
        int lc = i * 256 + tid;
        int v = lc >> 4, c = lc & 15;
        const float* src = Kg + kvbase + (size_t)(v0 + v) * HD + c * 8;
        float x[8];
        *(float4*)&x[0] = *(const float4*)src;
        *(float4*)&x[4] = *(const float4*)(src + 4);
        uint H[4], L[4];
#pragma unroll
        for (int k = 0; k < 4; ++k) {
            ushort h0 = bf16rne(x[2 * k]),     h1 = bf16rne(x[2 * k + 1]);
            ushort l0 = bf16rne(x[2 * k] - bf2f(h0));
            ushort l1 = bf16rne(x[2 * k + 1] - bf2f(h1));
            H[k] = (uint)h0 | ((uint)h1 << 16);
            L[k] = (uint)l0 | ((uint)l1 << 16);
        }
        int pos = CHK_K(v, c);
        *(uint4*)&dkh[pos] = *(uint4*)H;
        *(uint4*)&dkl[pos] = *(uint4*)L;
    }

    // V phase A: coalesced float4 row reads -> bf16 LDS tile [v][h]
#pragma unroll
    for (int i = 0; i < 8; ++i) {
        int idx = i * 256 + tid;
        int v = idx >> 5, hq = idx & 31;
        float4 a = *(const float4*)(Vg + kvbase + (size_t)(v0 + v) * HD + hq * 4);
        uint w0 = (uint)bf16rne(a.x) | ((uint)bf16rne(a.y) << 16);
        uint w1 = (uint)bf16rne(a.z) | ((uint)bf16rne(a.w) << 16);
        *(uint*)&vls[v * VLSTR + hq * 4]     = w0;
        *(uint*)&vls[v * VLSTR + hq * 4 + 2] = w1;
    }
    __syncthreads();
    // V phase B: transposed reads, chunk writes in OUTPUT order (coalesced)
#pragma unroll
    for (int i = 0; i < 4; ++i) {
        int oc = i * 256 + tid;
        int h = oc >> 3, swz = oc & 7;
        int c2 = (swz ^ h) & 7;
        uint Wd[4];
#pragma unroll
        for (int m = 0; m < 8; m += 2) {
            ushort a  = vls[(c2 * 8 + m) * VLSTR + h];
            ushort b2 = vls[(c2 * 8 + m + 1) * VLSTR + h];
            Wd[m >> 1] = (uint)a | ((uint)b2 << 16);
        }
        *(uint4*)&dvt[oc * 8] = *(uint4*)Wd;
    }
}

// ============================ main (fast path) ============================
// 256 threads = 4 waves, wave owns 16 rows x all 64 cols. One barrier/tile.
// Software-pipelined: PV(t-1) runs interleaved with QK(t); V triple-buffered.
// Fragment layouts (gfx950 mfma_f32_16x16x32_bf16, m89/m120-verified):
//   A: lane holds A[m = lane&15][k = (lane>>4)*8 + j]
//   B: lane holds B[k = (lane>>4)*8 + j][n = lane&15]
//   C/D: lane holds D[row = (lane>>4)*4 + reg][col = lane&15]
__global__ __launch_bounds__(256)
void fa_mfma4(const float* __restrict__ Qg, const ushort* __restrict__ Wk,
              float* __restrict__ Og) {
    __shared__ __align__(16) ushort kbuf[2][16384];  // K hi|lo double-buffer, 64 KB
    __shared__ __align__(16) ushort vbuf[3][8192];   // V^T triple-buffer, 48 KB
    __shared__ ushort pls[4][16 * PSTR];             // per-wave P round-trip, 9.2 KB

    const int tid  = threadIdx.x;
    const int wave = tid >> 6;
    const int lane = tid & 63;
    const int r    = lane & 15;
    const int qd   = lane >> 4;
    const int blockRow0 = blockIdx.x * 64;
    const int b = blockRow0 >> 12;
    const int waveRow0 = blockRow0 + wave * 16;
    const ushort* kvw = Wk + (size_t)b * 64 * TILE_USH;

    // Q -> A-fragments (hi/lo bf16 split), held in registers
    short8 qfh[4], qfl[4];
    {
        const float* qp = Qg + (size_t)(waveRow0 + r) * HD + qd * 8;
#pragma unroll
        for (int kc = 0; kc < 4; ++kc) {
            float x[8];
            *(float4*)&x[0] = *(const float4*)(qp + kc * 32);
            *(float4*)&x[4] = *(const float4*)(qp + kc * 32 + 4);
#pragma unroll
            for (int j = 0; j < 8; ++j) {
                ushort h = bf16rne(x[j]);
                qfh[kc][j] = (short)h;
                qfl[kc][j] = (short)bf16rne(x[j] - bf2f(h));
            }
        }
    }

    floatx4 oacc[8];
#pragma unroll
    for (int n = 0; n < 8; ++n) oacc[n] = (floatx4){0.f, 0.f, 0.f, 0.f};
    float m2[4] = {-INFINITY, -INFINITY, -INFINITY, -INFINITY};
    float lr[4] = {0.f, 0.f, 0.f, 0.f};

    // DMA one 48KB tile record: K 2048 chunks -> kbuf[ks], V 1024 -> vbuf[vs]
#define STAGE(tt, ks, vs) do { \
        const ushort* _sK = kvw + (size_t)(tt) * TILE_USH; \
        const ushort* _sV = _sK + 16384; \
        _Pragma("unroll") \
        for (int _i = 0; _i < 8; ++_i) \
            __builtin_amdgcn_global_load_lds((glb_u32*)(_sK + (_i * 256 + tid) * 8), \
                (lds_u32*)&kbuf[ks][(_i * 256 + wave * 64) * 8], 16, 0, 0); \
        _Pragma("unroll") \
        for (int _i = 0; _i < 4; ++_i) \
            __builtin_amdgcn_global_load_lds((glb_u32*)(_sV + (_i * 256 + tid) * 8), \
                (lds_u32*)&vbuf[vs][(_i * 256 + wave * 64) * 8], 16, 0, 0); \
    } while (0)

    STAGE(0, 0, 0);
    int vprev = 2, vcur = 0, vnext = 1;
    bool prevNeed = false;

    for (int t = 0; t < 64; ++t) {
        __syncthreads();   // drains vmcnt(0): tile t's DMA landed; tile t-1 reads done

        // prefetch t+1 immediately (kbuf[(t+1)&1] held K(t-1), done; vbuf[vnext] held V(t-2), done)
        if (t < 63) STAGE(t + 1, (t + 1) & 1, vnext);

        const ushort* KH = kbuf[t & 1];
        const ushort* KL = KH + 8192;
        const int v0 = t * 64;

        // ---- QK^T(t): 3-term bf16-split MFMA (stream 1) ----
        floatx4 cf[4];
#pragma unroll
        for (int nb = 0; nb < 4; ++nb) cf[nb] = (floatx4){0.f, 0.f, 0.f, 0.f};
#pragma unroll
        for (int kc = 0; kc < 4; ++kc) {
#pragma unroll
            for (int nb = 0; nb < 4; ++nb) {
                int ch = CHK_K(nb * 16 + r, kc * 4 + qd);
                short8 kh = *(const short8*)&KH[ch];
                short8 kl = *(const short8*)&KL[ch];
                cf[nb] = __builtin_amdgcn_mfma_f32_16x16x32_bf16(qfh[kc], kh, cf[nb], 0, 0, 0);
                cf[nb] = __builtin_amdgcn_mfma_f32_16x16x32_bf16(qfh[kc], kl, cf[nb], 0, 0, 0);
                cf[nb] = __builtin_amdgcn_mfma_f32_16x16x32_bf16(qfl[kc], kh, cf[nb], 0, 0, 0);
            }
        }

        // ---- PV(t-1): independent stream 2, interleaves with QK(t) ----
        if (prevNeed) {
            const ushort* VTp = vbuf[vprev];
#pragma unroll
            for (int kc2 = 0; kc2 < 2; ++kc2) {
                short8 pa = *(const short8*)&pls[wave][r * PSTR + kc2 * 32 + qd * 8];
#pragma unroll
                for (int n = 0; n < 8; ++n) {
                    short8 vb = *(const short8*)&VTp[CHK_V(n * 16 + r, kc2 * 4 + qd)];
                    oacc[n] = __builtin_amdgcn_mfma_f32_16x16x32_bf16(pa, vb, oacc[n], 0, 0, 0);
                }
            }
        }

        // ---- online softmax (exp2 domain), DPP reductions ----
        float ts[4][4], p[4][4];
#pragma unroll
        for (int nb = 0; nb < 4; ++nb)
#pragma unroll
            for (int g = 0; g < 4; ++g) ts[nb][g] = cf[nb][g] * SCL2E;

        float tsum[4], alpha[4], lnew[4];
#pragma unroll
        for (int g = 0; g < 4; ++g) {
            float tmx = fmaxf(fmaxf(ts[0][g], ts[1][g]), fmaxf(ts[2][g], ts[3][g]));
            tmx = row_max16(tmx);
            float mn = fmaxf(m2[g], tmx);
            alpha[g] = __builtin_amdgcn_exp2f(m2[g] - mn);
            m2[g] = mn;
        }
#pragma unroll
        for (int g = 0; g < 4; ++g) {
            float s = 0.f;
#pragma unroll
            for (int nb = 0; nb < 4; ++nb) {
                p[nb][g] = __builtin_amdgcn_exp2f(ts[nb][g] - m2[g]);
                s += p[nb][g];
            }
            s = row_sum16(s);
            tsum[g] = s;
            lnew[g] = lr[g] * alpha[g] + s;
            lr[g] = lnew[g];
        }

        bool rowneed = false;
#pragma unroll
        for (int g = 0; g < 4; ++g) rowneed |= (tsum[g] > EPS_SKIP * lnew[g]);
        bool act = __any(rowneed);

        if (act) {
            // rescale O (after PV(t-1) landed; alpha==1 exactly on skipped tiles)
#pragma unroll
            for (int n = 0; n < 8; ++n)
#pragma unroll
                for (int g = 0; g < 4; ++g) oacc[n][g] *= alpha[g];

            // dropout, gated per (nb,g) granule; write P(t) for next-iter PV
#pragma unroll
            for (int nb = 0; nb < 4; ++nb) {
#pragma unroll
                for (int g = 0; g < 4; ++g) {
                    if (__any(p[nb][g] > EPS_SKIP * lnew[g])) {
                        uint j = (uint)(waveRow0 + qd * 4 + g) * (uint)NV
                               + (uint)(v0 + nb * 16 + r);
                        if (threefry_bits(j) >= KEEP_THRESH) p[nb][g] = 0.f;
                    }
                    // bf16 truncation (1 op; ~0.2% downward bias, within budget)
                    pls[wave][(qd * 4 + g) * PSTR + nb * 16 + r] =
                        (ushort)(__float_as_uint(p[nb][g]) >> 16);
                }
            }
            __asm__ volatile("s_waitcnt lgkmcnt(0)" ::: "memory");  // own-wave P visible
        }
        prevNeed = act;
        vprev = vcur; vcur = vnext; vnext = 3 - vprev - vcur;
    }
#undef STAGE

    // flush PV(63)
    if (prevNeed) {
        const ushort* VTp = vbuf[vprev];
#pragma unroll
        for (int kc2 = 0; kc2 < 2; ++kc2) {
            short8 pa = *(const short8*)&pls[wave][r * PSTR + kc2 * 32 + qd * 8];
#pragma unroll
            for (int n = 0; n < 8; ++n) {
                short8 vb = *(const short8*)&VTp[CHK_V(n * 16 + r, kc2 * 4 + qd)];
                oacc[n] = __builtin_amdgcn_mfma_f32_16x16x32_bf16(pa, vb, oacc[n], 0, 0, 0);
            }
        }
    }

    // epilogue: out = acc / (0.9 * l)
    float inv[4];
#pragma unroll
    for (int g = 0; g < 4; ++g) inv[g] = 1.0f / (0.9f * lr[g]);
#pragma unroll
    for (int n = 0; n < 8; ++n)
#pragma unroll
        for (int g = 0; g < 4; ++g)
            Og[(size_t)(waveRow0 + qd * 4 + g) * HD + n * 16 + r] = oacc[n][g] * inv[g];
}

// ============================ fallback (round-3, verified) ============================
__global__ __launch_bounds__(256)
void fa_mfma(const float* __restrict__ Qg, const float* __restrict__ Kg,
             const float* __restrict__ Vg, float* __restrict__ Og) {
    __shared__ ushort khi[64 * KSTR];
    __shared__ ushort klo[64 * KSTR];
    __shared__ ushort vt[128 * VSTR];
    __shared__ ushort plsf[4][16 * PSTR];

    const int tid  = threadIdx.x;
    const int wave = tid >> 6;
    const int lane = tid & 63;
    const int r    = lane & 15;
    const int qd   = lane >> 4;
    const int blockRow0 = blockIdx.x * 64;
    const int b = blockRow0 >> 12;
    const int waveRow0 = blockRow0 + wave * 16;
    const size_t kvbase = (size_t)b * NV * HD;

    short8 qfh[4], qfl[4];
    {
        const float* qp = Qg + (size_t)(waveRow0 + r) * HD + qd * 8;
#pragma unroll
        for (int kc = 0; kc < 4; ++kc) {
            float x[8];
            *(float4*)&x[0] = *(const float4*)(qp + kc * 32);
            *(float4*)&x[4] = *(const float4*)(qp + kc * 32 + 4);
#pragma unroll
            for (int j = 0; j < 8; ++j) {
                ushort h = bf16rne(x[j]);
                qfh[kc][j] = (short)h;
                qfl[kc][j] = (short)bf16rne(x[j] - bf2f(h));
            }
        }
    }

    floatx4 oacc[8];
#pragma unroll
    for (int n = 0; n < 8; ++n) oacc[n] = (floatx4){0.f, 0.f, 0.f, 0.f};
    float m2[4] = {-INFINITY, -INFINITY, -INFINITY, -INFINITY};
    float lr[4] = {0.f, 0.f, 0.f, 0.f};

    for (int v0 = 0; v0 < NV; v0 += 64) {
        __syncthreads();
#pragma unroll
        for (int i = 0; i < 8; ++i) {
            int f = i * 256 + tid;
            int v = f >> 5;
            int h = (f & 31) * 4;
            float4 kv = *(const float4*)(Kg + kvbase + (size_t)(v0 + v) * HD + h);
            ushort4 hh, ll;
            hh.x = bf16rne(kv.x); ll.x = bf16rne(kv.x - bf2f(hh.x));
            hh.y = bf16rne(kv.y); ll.y = bf16rne(kv.y - bf2f(hh.y));
            hh.z = bf16rne(kv.z); ll.z = bf16rne(kv.z - bf2f(hh.z));
            hh.w = bf16rne(kv.w); ll.w = bf16rne(kv.w - bf2f(hh.w));
            *(ushort4*)&khi[v * KSTR + h] = hh;
            *(ushort4*)&klo[v * KSTR + h] = ll;
        }
        {
            int hp = tid & 63, rp = tid >> 6;
            int h = hp * 2;
            const float* vpb = Vg + kvbase + (size_t)v0 * HD + h;
#pragma unroll
            for (int i = 0; i < 8; ++i) {
                int v = i * 8 + rp * 2;
                float2 a = *(const float2*)(vpb + (size_t)v * HD);
                float2 c = *(const float2*)(vpb + (size_t)(v + 1) * HD);
                uint w0 = (uint)bf16rne(a.x) | ((uint)bf16rne(c.x) << 16);
                uint w1 = (uint)bf16rne(a.y) | ((uint)bf16rne(c.y) << 16);
                *(uint*)&vt[h * VSTR + v]       = w0;
                *(uint*)&vt[(h + 1) * VSTR + v] = w1;
            }
        }
        __syncthreads();

        floatx4 cf[4];
#pragma unroll
        for (int nb = 0; nb < 4; ++nb) cf[nb] = (floatx4){0.f, 0.f, 0.f, 0.f};
#pragma unroll
        for (int kc = 0; kc < 4; ++kc) {
#pragma unroll
            for (int nb = 0; nb < 4; ++nb) {
                int off = (nb * 16 + r) * KSTR + kc * 32 + qd * 8;
                short8 kh = *(const short8*)&khi[off];
                short8 kl = *(const short8*)&klo[off];
                cf[nb] = __builtin_amdgcn_mfma_f32_16x16x32_bf16(qfh[kc], kh, cf[nb], 0, 0, 0);
                cf[nb] = __builtin_amdgcn_mfma_f32_16x16x32_bf16(qfh[kc], kl, cf[nb], 0, 0, 0);
                cf[nb] = __builtin_amdgcn_mfma_f32_16x16x32_bf16(qfl[kc], kh, cf[nb], 0, 0, 0);
            }
        }

        float ts[4][4], p[4][4];
#pragma unroll
        for (int nb = 0; nb < 4; ++nb)
#pragma unroll
            for (int g = 0; g < 4; ++g) ts[nb][g] = cf[nb][g] * SCL2E;

        float tsum[4], alpha[4], lnew[4];
#pragma unroll
        for (int g = 0; g < 4; ++g) {
            float tmx = fmaxf(fmaxf(ts[0][g], ts[1][g]), fmaxf(ts[2][g], ts[3][g]));
#pragma unroll
            for (int off = 1; off < 16; off <<= 1)
                tmx = fmaxf(tmx, __shfl_xor(tmx, off));
            float mn = fmaxf(m2[g], tmx);
            alpha[g] = __builtin_amdgcn_exp2f(m2[g] - mn);
            m2[g] = mn;
        }
#pragma unroll
        for (int g = 0; g < 4; ++g) {
            float s = 0.f;
#pragma unroll
            for (int nb = 0; nb < 4; ++nb) {
                p[nb][g] = __builtin_amdgcn_exp2f(ts[nb][g] - m2[g]);
                s += p[nb][g];
            }
#pragma unroll
            for (int off = 1; off < 16; off <<= 1)
                s += __shfl_xor(s, off);
            tsum[g] = s;
            lnew[g] = lr[g] * alpha[g] + s;
            lr[g] = lnew[g];
        }

        bool rowneed = false;
#pragma unroll
        for (int g = 0; g < 4; ++g) rowneed |= (tsum[g] > 1e-8f * lnew[g]);

        if (__any(rowneed)) {
#pragma unroll
            for (int n = 0; n < 8; ++n)
#pragma unroll
                for (int g = 0; g < 4; ++g) oacc[n][g] *= alpha[g];

#pragma unroll
            for (int nb = 0; nb < 4; ++nb) {
                bool nbneed = false;
#pragma unroll
                for (int g = 0; g < 4; ++g) nbneed |= (p[nb][g] > 1e-8f * lnew[g]);
                if (__any(nbneed)) {
#pragma unroll
                    for (int g = 0; g < 4; ++g) {
                        uint j = (uint)(waveRow0 + qd * 4 + g) * (uint)NV
                               + (uint)(v0 + nb * 16 + r);
                        if (threefry_bits(j) >= KEEP_THRESH) p[nb][g] = 0.f;
                    }
                }
#pragma unroll
                for (int g = 0; g < 4; ++g)
                    plsf[wave][(qd * 4 + g) * PSTR + nb * 16 + r] = bf16rne(p[nb][g]);
            }
            __asm__ volatile("s_waitcnt lgkmcnt(0)" ::: "memory");

#pragma unroll
            for (int kc2 = 0; kc2 < 2; ++kc2) {
                short8 pa = *(const short8*)&plsf[wave][r * PSTR + kc2 * 32 + qd * 8];
#pragma unroll
                for (int n = 0; n < 8; ++n) {
                    int off = (n * 16 + r) * VSTR + kc2 * 32 + qd * 8;
                    ushort4 u0 = *(const ushort4*)&vt[off];
                    ushort4 u1 = *(const ushort4*)&vt[off + 4];
                    short8 vb;
                    vb[0] = (short)u0.x; vb[1] = (short)u0.y; vb[2] = (short)u0.z; vb[3] = (short)u0.w;
                    vb[4] = (short)u1.x; vb[5] = (short)u1.y; vb[6] = (short)u1.z; vb[7] = (short)u1.w;
                    oacc[n] = __builtin_amdgcn_mfma_f32_16x16x32_bf16(pa, vb, oacc[n], 0, 0, 0);
                }
            }
        }
    }

    float inv[4];
#pragma unroll
    for (int g = 0; g < 4; ++g) inv[g] = 1.0f / (0.9f * lr[g]);
#pragma unroll
    for (int n = 0; n < 8; ++n)
#pragma unroll
        for (int g = 0; g < 4; ++g)
            Og[(size_t)(waveRow0 + qd * 4 + g) * HD + n * 16 + r] = oacc[n][g] * inv[g];
}

extern "C" void kernel_launch(void* const* d_in, const int* in_sizes, int n_in,
                              void* d_out, int out_size, void* d_ws, size_t ws_size,
                              hipStream_t stream) {
    (void)in_sizes; (void)n_in; (void)out_size;
    const float* Qg = (const float*)d_in[0];
    const float* Kg = (const float*)d_in[1];
    const float* Vg = (const float*)d_in[2];
    float* Og = (float*)d_out;
    if (ws_size >= WS_NEEDED) {
        prepass<<<dim3(256), 256, 0, stream>>>(Kg, Vg, (ushort*)d_ws);
        fa_mfma4<<<dim3(NBATCH * NQ / 64), 256, 0, stream>>>(Qg, (const ushort*)d_ws, Og);
    } else {
        fa_mfma<<<dim3(NBATCH * NQ / 64), 256, 0, stream>>>(Qg, Kg, Vg, Og);
    }
}

// Round 7
// 222.297 us; speedup vs baseline: 3.9740x; 1.0643x over previous
//
#include <hip/hip_runtime.h>
#include <stdint.h>

// B=4, Q=4096, V=4096, H=128, fp32 in/out
#define NBATCH 4
#define NQ 4096
#define NV 4096
#define HD 128

// SCALE * log2(e): scores scaled into exp2 domain
#define SCL2E ((float)(11.31370849898476 * 1.4426950408889634))

// keep  <=>  bits < 0.9f in fixed point (0.9f = 7549747 * 2^-23)
#define KEEP_THRESH 3865470464u
#define EPS_SKIP 1e-6f

// --- ws layout (prepass output) ---
// per (batch,tile) record: [khi 8192 ush][klo 8192 ush][vt 8192 ush] = 48 KB
// chunk = 8 ushorts = 16B.  XOR-swizzled chunk positions (2-way bank = free):
#define CHK_K(v,c) ((((v) * 16) + (((c) ^ (v)) & 15)) * 8)   // v 0..63, c 0..15
#define CHK_V(h,c) ((((h) * 8)  + (((c) ^ (h)) & 7))  * 8)   // h 0..127, c 0..7
#define TILE_USH 24576
#define WS_NEEDED ((size_t)NBATCH * 64 * TILE_USH * 2)       // 12,582,912 B

#define PSTR2 40   // pls row stride (ushorts): 16 rows x 32 cols + pad
#define VLSTR 142  // prepass LDS v-tile stride (ushorts)

// --- fallback path constants (round-3 kernel, verified passing) ---
#define KSTR 144
#define VSTR 76
#define PSTR 72

typedef __attribute__((ext_vector_type(8))) short short8;   // 8 bf16 (MFMA A/B frag)
typedef __attribute__((ext_vector_type(4))) float floatx4;  // MFMA C/D frag
typedef unsigned int uint;
typedef unsigned short ushort;
typedef __attribute__((address_space(3))) uint lds_u32;
typedef __attribute__((address_space(1))) const uint glb_u32;

__device__ __forceinline__ ushort bf16rne(float f) {
    uint u = __float_as_uint(f);
    u = (u + 0x7fffu + ((u >> 16) & 1u)) >> 16;
    return (ushort)u;
}
__device__ __forceinline__ float bf2f(ushort h) {
    return __uint_as_float(((uint)h) << 16);
}

// ---- DPP 16-lane reductions (VALU-only, no DS pipe) ----
template <int CTRL>
__device__ __forceinline__ float dppmov(float x) {
    return __int_as_float(__builtin_amdgcn_update_dpp(
        0, __float_as_int(x), CTRL, 0xF, 0xF, true));
}
__device__ __forceinline__ float row_max16(float x) {
    x = fmaxf(x, dppmov<0xB1>(x));    // quad_perm xor1
    x = fmaxf(x, dppmov<0x4E>(x));    // quad_perm xor2
    x = fmaxf(x, dppmov<0x141>(x));   // row_half_mirror
    x = fmaxf(x, dppmov<0x140>(x));   // row_mirror
    return x;
}
__device__ __forceinline__ float row_sum16(float x) {
    x += dppmov<0xB1>(x);
    x += dppmov<0x4E>(x);
    x += dppmov<0x141>(x);
    x += dppmov<0x140>(x);
    return x;
}

__device__ __forceinline__ uint rotl(uint x, int r) { return (x << r) | (x >> (32 - r)); }

// JAX threefry2x32 partitionable path, key=(0,42): bits = y0 ^ y1 of hash of 64-bit counter j
__device__ __forceinline__ uint threefry_bits(uint j) {
    uint x0 = 0u;   // counter hi word (all j < 2^32)
    uint x1 = j;
    const uint k0 = 0u, k1 = 42u, k2 = 0u ^ 42u ^ 0x1BD11BDAu;
    x0 += k0; x1 += k1;
#define TFR4(a,b,c,d) \
    x0 += x1; x1 = rotl(x1, a); x1 ^= x0; \
    x0 += x1; x1 = rotl(x1, b); x1 ^= x0; \
    x0 += x1; x1 = rotl(x1, c); x1 ^= x0; \
    x0 += x1; x1 = rotl(x1, d); x1 ^= x0;
    TFR4(13, 15, 26, 6)
    x0 += k1; x1 += k2 + 1u;
    TFR4(17, 29, 16, 24)
    x0 += k2; x1 += k0 + 2u;
    TFR4(13, 15, 26, 6)
    x0 += k0; x1 += k1 + 3u;
    TFR4(17, 29, 16, 24)
    x0 += k1; x1 += k2 + 4u;
    TFR4(13, 15, 26, 6)
    x0 += k2; x1 += k0 + 5u;
#undef TFR4
    return x0 ^ x1;
}

// ============================ prepass ============================
// grid 512 = (4 batches x 64 tiles) x 2 halves. half 0: K convert; half 1: V transpose.
__global__ __launch_bounds__(256)
void prepass(const float* __restrict__ Kg, const float* __restrict__ Vg,
             ushort* __restrict__ W) {
    __shared__ ushort vls[64 * VLSTR];
    const int rec  = blockIdx.x >> 1;
    const int half = blockIdx.x & 1;
    const int bb = rec >> 6;
    const int t  = rec & 63;
    const int v0 = t * 64;
    const size_t kvbase = (size_t)bb * NV * HD;
    ushort* dst = W + ((size_t)bb * 64 + t) * TILE_USH;
    const int tid = threadIdx.x;

    if (half == 0) {
        // K: 1024 chunks (64 rows x 16 chunk-cols), hi/lo split, coalesced both sides
        ushort* dkh = dst;
        ushort* dkl = dst + 8192;
#pragma unroll
        for (int i = 0; i < 4; ++i) {
            int lc = i * 256 + tid;
            int v = lc >> 4, c = lc & 15;
            const float* src = Kg + kvbase + (size_t)(v0 + v) * HD + c * 8;
            float x[8];
            *(float4*)&x[0] = *(const float4*)src;
            *(float4*)&x[4] = *(const float4*)(src + 4);
            uint H[4], L[4];
#pragma unroll
            for (int k = 0; k < 4; ++k) {
                ushort h0 = bf16rne(x[2 * k]),     h1 = bf16rne(x[2 * k + 1]);
                ushort l0 = bf16rne(x[2 * k] - bf2f(h0));
                ushort l1 = bf16rne(x[2 * k + 1] - bf2f(h1));
                H[k] = (uint)h0 | ((uint)h1 << 16);
                L[k] = (uint)l0 | ((uint)l1 << 16);
            }
            int pos = CHK_K(v, c);
            *(uint4*)&dkh[pos] = *(uint4*)H;
            *(uint4*)&dkl[pos] = *(uint4*)L;
        }
    } else {
        // V phase A: coalesced float4 row reads -> bf16 LDS tile [v][h]
        ushort* dvt = dst + 16384;
#pragma unroll
        for (int i = 0; i < 8; ++i) {
            int idx = i * 256 + tid;
            int v = idx >> 5, hq = idx & 31;
            float4 a = *(const float4*)(Vg + kvbase + (size_t)(v0 + v) * HD + hq * 4);
            uint w0 = (uint)bf16rne(a.x) | ((uint)bf16rne(a.y) << 16);
            uint w1 = (uint)bf16rne(a.z) | ((uint)bf16rne(a.w) << 16);
            *(uint*)&vls[v * VLSTR + hq * 4]     = w0;
            *(uint*)&vls[v * VLSTR + hq * 4 + 2] = w1;
        }
        __syncthreads();
        // V phase B: transposed reads, chunk writes in OUTPUT order (coalesced)
#pragma unroll
        for (int i = 0; i < 4; ++i) {
            int oc = i * 256 + tid;
            int h = oc >> 3, swz = oc & 7;
            int c2 = (swz ^ h) & 7;
            uint Wd[4];
#pragma unroll
            for (int m = 0; m < 8; m += 2) {
                ushort a  = vls[(c2 * 8 + m) * VLSTR + h];
                ushort b2 = vls[(c2 * 8 + m + 1) * VLSTR + h];
                Wd[m >> 1] = (uint)a | ((uint)b2 << 16);
            }
            *(uint4*)&dvt[oc * 8] = *(uint4*)Wd;
        }
    }
}

// ============================ main (fast path) ============================
// grid 512 x 256 threads, 32 q-rows/block, ~70 KB LDS -> 2 blocks/CU:
// two independent barrier domains per CU so DS-phase (QK) of one block
// overlaps VALU-phase (softmax/threefry) of the other.
// Waves: wave = rg*2 + cw; rg = row-group (16 rows), cw = column half (32 cols).
// K single-buffered (2 barriers/tile), V double-buffered.
// Fragment layouts (gfx950 mfma_f32_16x16x32_bf16, m89/m120-verified):
//   A: lane holds A[m = lane&15][k = (lane>>4)*8 + j]
//   B: lane holds B[k = (lane>>4)*8 + j][n = lane&15]
//   C/D: lane holds D[row = (lane>>4)*4 + reg][col = lane&15]
__global__ __launch_bounds__(256, 2)
void fa_mfma5(const float* __restrict__ Qg, const ushort* __restrict__ Wk,
              float* __restrict__ Og) {
    __shared__ __align__(16) ushort kbuf[16384];     // K hi|lo, single, 32 KB
    __shared__ __align__(16) ushort vbuf[2][8192];   // V^T double, 32 KB
    __shared__ ushort pls[4][16 * PSTR2];            // per-wave P round-trip, 5 KB
    __shared__ float mrow[4][32];                    // (m_part,s_part) x 16 rows/wave

    const int tid  = threadIdx.x;
    const int wave = tid >> 6;
    const int lane = tid & 63;
    const int r    = lane & 15;
    const int qd   = lane >> 4;
    const int rg   = wave >> 1;
    const int cw   = wave & 1;
    const int blockRow0 = blockIdx.x * 32;
    const int b = blockRow0 >> 12;
    const int waveRow0 = blockRow0 + rg * 16;
    const ushort* kvw = Wk + (size_t)b * 64 * TILE_USH;

    // Q -> A-fragments (hi/lo bf16 split), registers
    short8 qfh[4], qfl[4];
    {
        const float* qp = Qg + (size_t)(waveRow0 + r) * HD + qd * 8;
#pragma unroll
        for (int kc = 0; kc < 4; ++kc) {
            float x[8];
            *(float4*)&x[0] = *(const float4*)(qp + kc * 32);
            *(float4*)&x[4] = *(const float4*)(qp + kc * 32 + 4);
#pragma unroll
            for (int j = 0; j < 8; ++j) {
                ushort h = bf16rne(x[j]);
                qfh[kc][j] = (short)h;
                qfl[kc][j] = (short)bf16rne(x[j] - bf2f(h));
            }
        }
    }

    floatx4 oacc[8];
#pragma unroll
    for (int n = 0; n < 8; ++n) oacc[n] = (floatx4){0.f, 0.f, 0.f, 0.f};
    float m2[4] = {-INFINITY, -INFINITY, -INFINITY, -INFINITY};
    float lr[4] = {0.f, 0.f, 0.f, 0.f};

    // DMA tile record tt: K 2048 chunks -> kbuf, V 1024 chunks -> vbuf[vs]
#define STAGE(tt, vs) do { \
        const ushort* _sK = kvw + (size_t)(tt) * TILE_USH; \
        const ushort* _sV = _sK + 16384; \
        _Pragma("unroll") \
        for (int _i = 0; _i < 8; ++_i) \
            __builtin_amdgcn_global_load_lds((glb_u32*)(_sK + (_i * 256 + tid) * 8), \
                (lds_u32*)&kbuf[(_i * 256 + wave * 64) * 8], 16, 0, 0); \
        _Pragma("unroll") \
        for (int _i = 0; _i < 4; ++_i) \
            __builtin_amdgcn_global_load_lds((glb_u32*)(_sV + (_i * 256 + tid) * 8), \
                (lds_u32*)&vbuf[vs][(_i * 256 + wave * 64) * 8], 16, 0, 0); \
    } while (0)

    STAGE(0, 0);

    for (int t = 0; t < 64; ++t) {
        __syncthreads();   // B1: drains DMA(t) [vmcnt(0)]; PV(t-1) V-reads done

        const ushort* KH = kbuf;
        const ushort* KL = kbuf + 8192;
        const int v0 = t * 64;

        // ---- QK^T(t) over this wave's 32 cols: 3-term bf16-split MFMA ----
        floatx4 cf[2];
        cf[0] = (floatx4){0.f, 0.f, 0.f, 0.f};
        cf[1] = (floatx4){0.f, 0.f, 0.f, 0.f};
#pragma unroll
        for (int kc = 0; kc < 4; ++kc) {
#pragma unroll
            for (int nb = 0; nb < 2; ++nb) {
                int ch = CHK_K(cw * 32 + nb * 16 + r, kc * 4 + qd);
                short8 kh = *(const short8*)&KH[ch];
                short8 kl = *(const short8*)&KL[ch];
                cf[nb] = __builtin_amdgcn_mfma_f32_16x16x32_bf16(qfh[kc], kh, cf[nb], 0, 0, 0);
                cf[nb] = __builtin_amdgcn_mfma_f32_16x16x32_bf16(qfh[kc], kl, cf[nb], 0, 0, 0);
                cf[nb] = __builtin_amdgcn_mfma_f32_16x16x32_bf16(qfl[kc], kh, cf[nb], 0, 0, 0);
            }
        }

        // ---- local softmax partials (per row, over this wave's 32 cols) ----
        float ts[2][4], pp[2][4], tm[4], sp[4];
#pragma unroll
        for (int nb = 0; nb < 2; ++nb)
#pragma unroll
            for (int g = 0; g < 4; ++g) ts[nb][g] = cf[nb][g] * SCL2E;
#pragma unroll
        for (int g = 0; g < 4; ++g) {
            float tmx = row_max16(fmaxf(ts[0][g], ts[1][g]));
            tm[g] = tmx;
            float s = 0.f;
#pragma unroll
            for (int nb = 0; nb < 2; ++nb) {
                pp[nb][g] = __builtin_amdgcn_exp2f(ts[nb][g] - tmx);
                s += pp[nb][g];
            }
            sp[g] = row_sum16(s);
        }
        if (r == 0) {
#pragma unroll
            for (int g = 0; g < 4; ++g) {
                mrow[wave][(qd * 4 + g) * 2]     = tm[g];
                mrow[wave][(qd * 4 + g) * 2 + 1] = sp[g];
            }
        }
        __syncthreads();   // B2: mrow visible; QK reads of kbuf done (no vmem pending)

        if (t < 63) STAGE(t + 1, (t + 1) & 1);   // K(t+1) may overwrite kbuf now

        // ---- pair merge + online update (both waves compute identically) ----
        float alpha[4], beta[4];
        bool rowneed = false;
#pragma unroll
        for (int g = 0; g < 4; ++g) {
            float mo = mrow[wave ^ 1][(qd * 4 + g) * 2];
            float so = mrow[wave ^ 1][(qd * 4 + g) * 2 + 1];
            float mt = fmaxf(tm[g], mo);
            float mn = fmaxf(m2[g], mt);
            alpha[g] = __builtin_amdgcn_exp2f(m2[g] - mn);
            beta[g]  = __builtin_amdgcn_exp2f(tm[g] - mn);
            float tsum = sp[g] * beta[g] + so * __builtin_amdgcn_exp2f(mo - mn);
            float lnew = lr[g] * alpha[g] + tsum;
            lr[g] = lnew;
            m2[g] = mn;
            rowneed |= (tsum > EPS_SKIP * lnew);
        }

        if (__any(rowneed)) {
            // rescale O (alpha==1 exactly on skipped tiles)
#pragma unroll
            for (int n = 0; n < 8; ++n)
#pragma unroll
                for (int g = 0; g < 4; ++g) oacc[n][g] *= alpha[g];

            // dropout, gated per (nb,g) granule (4 rows x 16 cols)
#pragma unroll
            for (int nb = 0; nb < 2; ++nb) {
#pragma unroll
                for (int g = 0; g < 4; ++g) {
                    float pf = pp[nb][g] * beta[g];
                    if (__any(pf > EPS_SKIP * lr[g])) {
                        uint j = (uint)(waveRow0 + qd * 4 + g) * (uint)NV
                               + (uint)(v0 + cw * 32 + nb * 16 + r);
                        if (threefry_bits(j) >= KEEP_THRESH) pf = 0.f;
                    }
                    // bf16 truncation (1 op; ~0.2% downward bias, within budget)
                    pls[wave][(qd * 4 + g) * PSTR2 + nb * 16 + r] =
                        (ushort)(__float_as_uint(pf) >> 16);
                }
            }
            __asm__ volatile("s_waitcnt lgkmcnt(0)" ::: "memory");  // own-wave P visible

            // ---- PV(t) over this wave's 32 v's: one K=32 MFMA per n ----
            const ushort* VT = vbuf[t & 1];
            short8 pa = *(const short8*)&pls[wave][r * PSTR2 + qd * 8];
#pragma unroll
            for (int n = 0; n < 8; ++n) {
                short8 vb = *(const short8*)&VT[CHK_V(n * 16 + r, cw * 4 + qd)];
                oacc[n] = __builtin_amdgcn_mfma_f32_16x16x32_bf16(pa, vb, oacc[n], 0, 0, 0);
            }
        }
    }
#undef STAGE

    // ---- epilogue: sum wave-pair partial O via kbuf (free now), normalize ----
    float* ob = (float*)&kbuf[0];   // 2 rg x 16 rows x 128 cols = 16 KB
    if (cw == 1) {
#pragma unroll
        for (int n = 0; n < 8; ++n)
#pragma unroll
            for (int g = 0; g < 4; ++g)
                ob[rg * 2048 + (qd * 4 + g) * 128 + n * 16 + r] = oacc[n][g];
    }
    __syncthreads();
    if (cw == 0) {
        float inv[4];
#pragma unroll
        for (int g = 0; g < 4; ++g) inv[g] = 1.0f / (0.9f * lr[g]);
#pragma unroll
        for (int n = 0; n < 8; ++n)
#pragma unroll
            for (int g = 0; g < 4; ++g) {
                float o = oacc[n][g] + ob[rg * 2048 + (qd * 4 + g) * 128 + n * 16 + r];
                Og[(size_t)(waveRow0 + qd * 4 + g) * HD + n * 16 + r] = o * inv[g];
            }
    }
}

// ============================ fallback (round-3, verified) ============================
__global__ __launch_bounds__(256)
void fa_mfma(const float* __restrict__ Qg, const float* __restrict__ Kg,
             const float* __restrict__ Vg, float* __restrict__ Og) {
    __shared__ ushort khi[64 * KSTR];
    __shared__ ushort klo[64 * KSTR];
    __shared__ ushort vt[128 * VSTR];
    __shared__ ushort plsf[4][16 * PSTR];

    const int tid  = threadIdx.x;
    const int wave = tid >> 6;
    const int lane = tid & 63;
    const int r    = lane & 15;
    const int qd   = lane >> 4;
    const int blockRow0 = blockIdx.x * 64;
    const int b = blockRow0 >> 12;
    const int waveRow0 = blockRow0 + wave * 16;
    const size_t kvbase = (size_t)b * NV * HD;

    short8 qfh[4], qfl[4];
    {
        const float* qp = Qg + (size_t)(waveRow0 + r) * HD + qd * 8;
#pragma unroll
        for (int kc = 0; kc < 4; ++kc) {
            float x[8];
            *(float4*)&x[0] = *(const float4*)(qp + kc * 32);
            *(float4*)&x[4] = *(const float4*)(qp + kc * 32 + 4);
#pragma unroll
            for (int j = 0; j < 8; ++j) {
                ushort h = bf16rne(x[j]);
                qfh[kc][j] = (short)h;
                qfl[kc][j] = (short)bf16rne(x[j] - bf2f(h));
            }
        }
    }

    floatx4 oacc[8];
#pragma unroll
    for (int n = 0; n < 8; ++n) oacc[n] = (floatx4){0.f, 0.f, 0.f, 0.f};
    float m2[4] = {-INFINITY, -INFINITY, -INFINITY, -INFINITY};
    float lr[4] = {0.f, 0.f, 0.f, 0.f};

    for (int v0 = 0; v0 < NV; v0 += 64) {
        __syncthreads();
#pragma unroll
        for (int i = 0; i < 8; ++i) {
            int f = i * 256 + tid;
            int v = f >> 5;
            int h = (f & 31) * 4;
            float4 kv = *(const float4*)(Kg + kvbase + (size_t)(v0 + v) * HD + h);
            ushort4 hh, ll;
            hh.x = bf16rne(kv.x); ll.x = bf16rne(kv.x - bf2f(hh.x));
            hh.y = bf16rne(kv.y); ll.y = bf16rne(kv.y - bf2f(hh.y));
            hh.z = bf16rne(kv.z); ll.z = bf16rne(kv.z - bf2f(hh.z));
            hh.w = bf16rne(kv.w); ll.w = bf16rne(kv.w - bf2f(hh.w));
            *(ushort4*)&khi[v * KSTR + h] = hh;
            *(ushort4*)&klo[v * KSTR + h] = ll;
        }
        {
            int hp = tid & 63, rp = tid >> 6;
            int h = hp * 2;
            const float* vpb = Vg + kvbase + (size_t)v0 * HD + h;
#pragma unroll
            for (int i = 0; i < 8; ++i) {
                int v = i * 8 + rp * 2;
                float2 a = *(const float2*)(vpb + (size_t)v * HD);
                float2 c = *(const float2*)(vpb + (size_t)(v + 1) * HD);
                uint w0 = (uint)bf16rne(a.x) | ((uint)bf16rne(c.x) << 16);
                uint w1 = (uint)bf16rne(a.y) | ((uint)bf16rne(c.y) << 16);
                *(uint*)&vt[h * VSTR + v]       = w0;
                *(uint*)&vt[(h + 1) * VSTR + v] = w1;
            }
        }
        __syncthreads();

        floatx4 cf[4];
#pragma unroll
        for (int nb = 0; nb < 4; ++nb) cf[nb] = (floatx4){0.f, 0.f, 0.f, 0.f};
#pragma unroll
        for (int kc = 0; kc < 4; ++kc) {
#pragma unroll
            for (int nb = 0; nb < 4; ++nb) {
                int off = (nb * 16 + r) * KSTR + kc * 32 + qd * 8;
                short8 kh = *(const short8*)&khi[off];
                short8 kl = *(const short8*)&klo[off];
                cf[nb] = __builtin_amdgcn_mfma_f32_16x16x32_bf16(qfh[kc], kh, cf[nb], 0, 0, 0);
                cf[nb] = __builtin_amdgcn_mfma_f32_16x16x32_bf16(qfh[kc], kl, cf[nb], 0, 0, 0);
                cf[nb] = __builtin_amdgcn_mfma_f32_16x16x32_bf16(qfl[kc], kh, cf[nb], 0, 0, 0);
            }
        }

        float ts[4][4], p[4][4];
#pragma unroll
        for (int nb = 0; nb < 4; ++nb)
#pragma unroll
            for (int g = 0; g < 4; ++g) ts[nb][g] = cf[nb][g] * SCL2E;

        float tsum[4], alpha[4], lnew[4];
#pragma unroll
        for (int g = 0; g < 4; ++g) {
            float tmx = fmaxf(fmaxf(ts[0][g], ts[1][g]), fmaxf(ts[2][g], ts[3][g]));
#pragma unroll
            for (int off = 1; off < 16; off <<= 1)
                tmx = fmaxf(tmx, __shfl_xor(tmx, off));
            float mn = fmaxf(m2[g], tmx);
            alpha[g] = __builtin_amdgcn_exp2f(m2[g] - mn);
            m2[g] = mn;
        }
#pragma unroll
        for (int g = 0; g < 4; ++g) {
            float s = 0.f;
#pragma unroll
            for (int nb = 0; nb < 4; ++nb) {
                p[nb][g] = __builtin_amdgcn_exp2f(ts[nb][g] - m2[g]);
                s += p[nb][g];
            }
#pragma unroll
            for (int off = 1; off < 16; off <<= 1)
                s += __shfl_xor(s, off);
            tsum[g] = s;
            lnew[g] = lr[g] * alpha[g] + s;
            lr[g] = lnew[g];
        }

        bool rowneed = false;
#pragma unroll
        for (int g = 0; g < 4; ++g) rowneed |= (tsum[g] > 1e-8f * lnew[g]);

        if (__any(rowneed)) {
#pragma unroll
            for (int n = 0; n < 8; ++n)
#pragma unroll
                for (int g = 0; g < 4; ++g) oacc[n][g] *= alpha[g];

#pragma unroll
            for (int nb = 0; nb < 4; ++nb) {
                bool nbneed = false;
#pragma unroll
                for (int g = 0; g < 4; ++g) nbneed |= (p[nb][g] > 1e-8f * lnew[g]);
                if (__any(nbneed)) {
#pragma unroll
                    for (int g = 0; g < 4; ++g) {
                        uint j = (uint)(waveRow0 + qd * 4 + g) * (uint)NV
                               + (uint)(v0 + nb * 16 + r);
                        if (threefry_bits(j) >= KEEP_THRESH) p[nb][g] = 0.f;
                    }
                }
#pragma unroll
                for (int g = 0; g < 4; ++g)
                    plsf[wave][(qd * 4 + g) * PSTR + nb * 16 + r] = bf16rne(p[nb][g]);
            }
            __asm__ volatile("s_waitcnt lgkmcnt(0)" ::: "memory");

#pragma unroll
            for (int kc2 = 0; kc2 < 2; ++kc2) {
                short8 pa = *(const short8*)&plsf[wave][r * PSTR + kc2 * 32 + qd * 8];
#pragma unroll
                for (int n = 0; n < 8; ++n) {
                    int off = (n * 16 + r) * VSTR + kc2 * 32 + qd * 8;
                    ushort4 u0 = *(const ushort4*)&vt[off];
                    ushort4 u1 = *(const ushort4*)&vt[off + 4];
                    short8 vb;
                    vb[0] = (short)u0.x; vb[1] = (short)u0.y; vb[2] = (short)u0.z; vb[3] = (short)u0.w;
                    vb[4] = (short)u1.x; vb[5] = (short)u1.y; vb[6] = (short)u1.z; vb[7] = (short)u1.w;
                    oacc[n] = __builtin_amdgcn_mfma_f32_16x16x32_bf16(pa, vb, oacc[n], 0, 0, 0);
                }
            }
        }
    }

    float inv[4];
#pragma unroll
    for (int g = 0; g < 4; ++g) inv[g] = 1.0f / (0.9f * lr[g]);
#pragma unroll
    for (int n = 0; n < 8; ++n)
#pragma unroll
        for (int g = 0; g < 4; ++g)
            Og[(size_t)(waveRow0 + qd * 4 + g) * HD + n * 16 + r] = oacc[n][g] * inv[g];
}

extern "C" void kernel_launch(void* const* d_in, const int* in_sizes, int n_in,
                              void* d_out, int out_size, void* d_ws, size_t ws_size,
                              hipStream_t stream) {
    (void)in_sizes; (void)n_in; (void)out_size;
    const float* Qg = (const float*)d_in[0];
    const float* Kg = (const float*)d_in[1];
    const float* Vg = (const float*)d_in[2];
    float* Og = (float*)d_out;
    if (ws_size >= WS_NEEDED) {
        prepass<<<dim3(512), 256, 0, stream>>>(Kg, Vg, (ushort*)d_ws);
        fa_mfma5<<<dim3(NBATCH * NQ / 32), 256, 0, stream>>>(Qg, (const ushort*)d_ws, Og);
    } else {
        fa_mfma<<<dim3(NBATCH * NQ / 64), 256, 0, stream>>>(Qg, Kg, Vg, Og);
    }
}